// Round 1
// baseline (4247.331 us; speedup 1.0000x reference)
//
#include <hip/hip_runtime.h>

#define N_NODES 50000
#define D       256
#define E_EDGES 400000
#define LN_EPS  1e-5f

// ---------------------------------------------------------------------------
// Kernel 1: Wsum = (W0 + W1 + W2) / 3
// (attention weights: softmax over size-1 tensors == 1, softmax([1,1,1]) ==
//  exactly 1/3 each, independent of a0/a1/a2 values -> fold into W sum)
// ---------------------------------------------------------------------------
__global__ __launch_bounds__(256) void k_wsum(const float* __restrict__ W0,
                                              const float* __restrict__ W1,
                                              const float* __restrict__ W2,
                                              float* __restrict__ Wsum) {
    int i = blockIdx.x * 256 + threadIdx.x;
    if (i < D * D) Wsum[i] = (W0[i] + W1[i] + W2[i]) * (1.0f / 3.0f);
}

// ---------------------------------------------------------------------------
// Kernel 2: per-relation degree counts
// ---------------------------------------------------------------------------
__global__ __launch_bounds__(256) void k_deg(const int* __restrict__ dst0,
                                             const int* __restrict__ dst1,
                                             const int* __restrict__ dst2,
                                             int* __restrict__ deg) {
    int i = blockIdx.x * 256 + threadIdx.x;
    if (i >= 3 * E_EDGES) return;
    int r = i / E_EDGES;
    int j = i - r * E_EDGES;
    const int* d = (r == 0) ? dst0 : (r == 1) ? dst1 : dst2;
    atomicAdd(&deg[r * N_NODES + d[j]], 1);
}

// ---------------------------------------------------------------------------
// Kernel 3: h = feat @ Wsum   [N,256] x [256,256] fp32
// Block: 256 threads, 32 rows x 256 cols per block.
// Thread t: col-quad c = t&63, row-group g = t>>6 (8 rows each).
// feat tile staged in LDS (32 KB); W rows streamed from L2 (hot, 256 KB).
// LDS read sfeat[g*8+rr][k]: all 64 lanes of a wave share g -> broadcast,
// conflict-free.
// ---------------------------------------------------------------------------
#define GEMM_ROWS 32
__global__ __launch_bounds__(256) void k_gemm(const float* __restrict__ feat,
                                              const float* __restrict__ Wsum,
                                              float* __restrict__ h) {
    __shared__ float sfeat[GEMM_ROWS][D];
    const int row0 = blockIdx.x * GEMM_ROWS;
    const int t = threadIdx.x;

    const float4* feat4 = (const float4*)feat;
    float4* sfeat4 = (float4*)&sfeat[0][0];
#pragma unroll
    for (int i = 0; i < 8; ++i) {
        int idx = i * 256 + t;        // float4 index within 32x64-f4 tile
        int rr = idx >> 6;
        int cc = idx & 63;
        int row = row0 + rr;
        float4 v = make_float4(0.f, 0.f, 0.f, 0.f);
        if (row < N_NODES) v = feat4[(size_t)row * 64 + cc];
        sfeat4[idx] = v;
    }
    __syncthreads();

    const int c = t & 63;
    const int g = t >> 6;
    float4 acc[8];
#pragma unroll
    for (int rr = 0; rr < 8; ++rr) acc[rr] = make_float4(0.f, 0.f, 0.f, 0.f);

    const float4* W4 = (const float4*)Wsum;
#pragma unroll 4
    for (int k = 0; k < D; ++k) {
        float4 wv = W4[k * 64 + c];
#pragma unroll
        for (int rr = 0; rr < 8; ++rr) {
            float f = sfeat[g * 8 + rr][k];
            acc[rr].x = fmaf(f, wv.x, acc[rr].x);
            acc[rr].y = fmaf(f, wv.y, acc[rr].y);
            acc[rr].z = fmaf(f, wv.z, acc[rr].z);
            acc[rr].w = fmaf(f, wv.w, acc[rr].w);
        }
    }

    float4* h4 = (float4*)h;
#pragma unroll
    for (int rr = 0; rr < 8; ++rr) {
        int row = row0 + g * 8 + rr;
        if (row < N_NODES) h4[(size_t)row * 64 + c] = acc[rr];
    }
}

// ---------------------------------------------------------------------------
// Kernel 4: scatter-add  out[dst] += h[src] / (3*max(deg,1))
// One wave (64 lanes x float4) per edge; 4 edges per 256-thread block.
// ---------------------------------------------------------------------------
__global__ __launch_bounds__(256) void k_scatter(const float* __restrict__ h,
                                                 const int* __restrict__ src0,
                                                 const int* __restrict__ dst0,
                                                 const int* __restrict__ src1,
                                                 const int* __restrict__ dst1,
                                                 const int* __restrict__ src2,
                                                 const int* __restrict__ dst2,
                                                 const int* __restrict__ deg,
                                                 float* __restrict__ out) {
    int wid = blockIdx.x * 4 + (threadIdx.x >> 6);
    if (wid >= 3 * E_EDGES) return;
    int lane = threadIdx.x & 63;
    int r = wid / E_EDGES;
    int j = wid - r * E_EDGES;
    const int* sp = (r == 0) ? src0 : (r == 1) ? src1 : src2;
    const int* dp = (r == 0) ? dst0 : (r == 1) ? dst1 : dst2;
    int s = sp[j];
    int d = dp[j];
    int dg = deg[r * N_NODES + d];
    float w = 1.0f / (3.0f * (float)(dg > 1 ? dg : 1));

    const float4* h4 = (const float4*)h;
    float4 v = h4[(size_t)s * 64 + lane];
    float* o = out + (size_t)d * D + lane * 4;
    atomicAdd(o + 0, v.x * w);
    atomicAdd(o + 1, v.y * w);
    atomicAdd(o + 2, v.z * w);
    atomicAdd(o + 3, v.w * w);
}

// ---------------------------------------------------------------------------
// Kernel 5: in-place ReLU + LayerNorm over each 256-float row.
// One wave per row (lane holds 4 cols), 64-lane shuffle reduction.
// ---------------------------------------------------------------------------
__global__ __launch_bounds__(256) void k_final(float* __restrict__ out,
                                               const float* __restrict__ gamma,
                                               const float* __restrict__ beta) {
    int row = blockIdx.x * 4 + (threadIdx.x >> 6);
    if (row >= N_NODES) return;
    int lane = threadIdx.x & 63;

    float4* o4 = (float4*)out;
    float4 v = o4[(size_t)row * 64 + lane];
    v.x = fmaxf(v.x, 0.f);
    v.y = fmaxf(v.y, 0.f);
    v.z = fmaxf(v.z, 0.f);
    v.w = fmaxf(v.w, 0.f);

    float s  = v.x + v.y + v.z + v.w;
    float ss = v.x * v.x + v.y * v.y + v.z * v.z + v.w * v.w;
#pragma unroll
    for (int off = 32; off > 0; off >>= 1) {
        s  += __shfl_xor(s, off, 64);
        ss += __shfl_xor(ss, off, 64);
    }
    float mean = s * (1.0f / D);
    float var  = ss * (1.0f / D) - mean * mean;
    float inv  = rsqrtf(var + LN_EPS);

    float4 gm = ((const float4*)gamma)[lane];
    float4 bt = ((const float4*)beta)[lane];
    float4 rv;
    rv.x = (v.x - mean) * inv * gm.x + bt.x;
    rv.y = (v.y - mean) * inv * gm.y + bt.y;
    rv.z = (v.z - mean) * inv * gm.z + bt.z;
    rv.w = (v.w - mean) * inv * gm.w + bt.w;
    o4[(size_t)row * 64 + lane] = rv;
}

// ---------------------------------------------------------------------------
extern "C" void kernel_launch(void* const* d_in, const int* in_sizes, int n_in,
                              void* d_out, int out_size, void* d_ws, size_t ws_size,
                              hipStream_t stream) {
    const float* feat  = (const float*)d_in[0];
    const float* W0    = (const float*)d_in[1];
    const float* W1    = (const float*)d_in[2];
    const float* W2    = (const float*)d_in[3];
    // d_in[4..6] = a0,a1,a2: unused — softmax of singletons makes w == 1/3 exactly
    const float* gamma = (const float*)d_in[7];
    const float* beta  = (const float*)d_in[8];
    const int* src0 = (const int*)d_in[9];
    const int* dst0 = (const int*)d_in[10];
    const int* src1 = (const int*)d_in[11];
    const int* dst1 = (const int*)d_in[12];
    const int* src2 = (const int*)d_in[13];
    const int* dst2 = (const int*)d_in[14];
    float* out = (float*)d_out;

    // workspace layout: Wsum [256 KB] | h [51.2 MB] | deg [600 KB]
    float* Wsum = (float*)d_ws;
    float* h    = Wsum + D * D;
    int*   deg  = (int*)(h + (size_t)N_NODES * D);

    // out doubles as the segment-sum accumulator: zero it (harness poisons 0xAA)
    hipMemsetAsync(d_out, 0, (size_t)N_NODES * D * sizeof(float), stream);
    hipMemsetAsync(deg, 0, 3 * N_NODES * sizeof(int), stream);

    k_wsum<<<(D * D + 255) / 256, 256, 0, stream>>>(W0, W1, W2, Wsum);
    k_deg<<<(3 * E_EDGES + 255) / 256, 256, 0, stream>>>(dst0, dst1, dst2, deg);
    k_gemm<<<(N_NODES + GEMM_ROWS - 1) / GEMM_ROWS, 256, 0, stream>>>(feat, Wsum, h);
    k_scatter<<<(3 * E_EDGES + 3) / 4, 256, 0, stream>>>(h, src0, dst0, src1, dst1,
                                                         src2, dst2, deg, out);
    k_final<<<(N_NODES + 3) / 4, 256, 0, stream>>>(out, gamma, beta);
}

// Round 2
// 510.579 us; speedup vs baseline: 8.3187x; 8.3187x over previous
//
#include <hip/hip_runtime.h>

#define N_NODES 50000
#define D       256
#define E_EDGES 400000
#define LN_EPS  1e-5f

#define SCAN_N  (3 * N_NODES)                       // 150000
#define SCAN_B  1024                                // elems per scan block
#define SCAN_NB ((SCAN_N + SCAN_B - 1) / SCAN_B)    // 147

// ---------------------------------------------------------------------------
// Kernel 1: Wsum = (W0 + W1 + W2) / 3
// (attention weights: softmax over size-1 tensors == 1, softmax([1,1,1]) ==
//  exactly 1/3 each, independent of a0/a1/a2 values -> fold into W sum)
// ---------------------------------------------------------------------------
__global__ __launch_bounds__(256) void k_wsum(const float* __restrict__ W0,
                                              const float* __restrict__ W1,
                                              const float* __restrict__ W2,
                                              float* __restrict__ Wsum) {
    int i = blockIdx.x * 256 + threadIdx.x;
    if (i < D * D) Wsum[i] = (W0[i] + W1[i] + W2[i]) * (1.0f / 3.0f);
}

// ---------------------------------------------------------------------------
// Kernel 2: per-relation degree counts (int atomics, cheap)
// ---------------------------------------------------------------------------
__global__ __launch_bounds__(256) void k_deg(const int* __restrict__ dst0,
                                             const int* __restrict__ dst1,
                                             const int* __restrict__ dst2,
                                             int* __restrict__ deg) {
    int i = blockIdx.x * 256 + threadIdx.x;
    if (i >= 3 * E_EDGES) return;
    int r = i / E_EDGES;
    int j = i - r * E_EDGES;
    const int* d = (r == 0) ? dst0 : (r == 1) ? dst1 : dst2;
    atomicAdd(&deg[r * N_NODES + d[j]], 1);
}

// ---------------------------------------------------------------------------
// Scan kernels: exclusive prefix sum of deg[SCAN_N] -> off[SCAN_N]
// scan1: per-block (1024 elems) local exclusive scan + block sums
// scan2: single block scans the 147 block sums in-place (-> exclusive bases)
// scan3: add block base
// ---------------------------------------------------------------------------
__global__ __launch_bounds__(256) void k_scan1(const int* __restrict__ deg,
                                               int* __restrict__ off,
                                               int* __restrict__ bsum) {
    __shared__ int wsum[4];
    const int t = threadIdx.x;
    const int base = blockIdx.x * SCAN_B + t * 4;
    int4 v = make_int4(0, 0, 0, 0);
    if (base < SCAN_N) v = *(const int4*)(deg + base);  // SCAN_N % 4 == 0
    const int s1 = v.x + v.y;
    const int s2 = s1 + v.z;
    const int s3 = s2 + v.w;
    const int lane = t & 63;
    int x = s3;                       // wave inclusive scan of per-thread sums
#pragma unroll
    for (int o2 = 1; o2 < 64; o2 <<= 1) {
        int y = __shfl_up(x, o2, 64);
        if (lane >= o2) x += y;
    }
    if (lane == 63) wsum[t >> 6] = x;
    const int texcl = x - s3;
    __syncthreads();
    int wbase = 0;
#pragma unroll
    for (int wi = 0; wi < 4; ++wi)
        if (wi < (t >> 6)) wbase += wsum[wi];
    const int ex = wbase + texcl;
    if (base < SCAN_N) {
        int4 o4;
        o4.x = ex; o4.y = ex + v.x; o4.z = ex + s1; o4.w = ex + s2;
        *(int4*)(off + base) = o4;
    }
    if (t == 0) bsum[blockIdx.x] = wsum[0] + wsum[1] + wsum[2] + wsum[3];
}

__global__ __launch_bounds__(256) void k_scan2(int* __restrict__ bsum) {
    __shared__ int wsum[4];
    const int t = threadIdx.x;
    const int v = (t < SCAN_NB) ? bsum[t] : 0;
    const int lane = t & 63;
    int x = v;
#pragma unroll
    for (int o2 = 1; o2 < 64; o2 <<= 1) {
        int y = __shfl_up(x, o2, 64);
        if (lane >= o2) x += y;
    }
    if (lane == 63) wsum[t >> 6] = x;
    __syncthreads();
    int wbase = 0;
#pragma unroll
    for (int wi = 0; wi < 4; ++wi)
        if (wi < (t >> 6)) wbase += wsum[wi];
    if (t < SCAN_NB) bsum[t] = wbase + x - v;   // exclusive base, in-place
}

__global__ __launch_bounds__(256) void k_scan3(int* __restrict__ off,
                                               const int* __restrict__ bsum) {
    int i = blockIdx.x * 256 + threadIdx.x;
    if (i < SCAN_N) off[i] += bsum[i >> 10];
}

// ---------------------------------------------------------------------------
// Kernel: bucket fill. pos = off[bucket]++ (atomic); eidx[pos] = src.
// After this kernel, off[bucket] == bucket END (start = end - deg).
// ---------------------------------------------------------------------------
__global__ __launch_bounds__(256) void k_fill(const int* __restrict__ src0,
                                              const int* __restrict__ dst0,
                                              const int* __restrict__ src1,
                                              const int* __restrict__ dst1,
                                              const int* __restrict__ src2,
                                              const int* __restrict__ dst2,
                                              int* __restrict__ off,
                                              int* __restrict__ eidx) {
    int i = blockIdx.x * 256 + threadIdx.x;
    if (i >= 3 * E_EDGES) return;
    int r = i / E_EDGES;
    int j = i - r * E_EDGES;
    const int* sp = (r == 0) ? src0 : (r == 1) ? src1 : src2;
    const int* dp = (r == 0) ? dst0 : (r == 1) ? dst1 : dst2;
    int pos = atomicAdd(&off[r * N_NODES + dp[j]], 1);
    eidx[pos] = sp[j];
}

// ---------------------------------------------------------------------------
// Kernel 3: h = feat @ Wsum   [N,256] x [256,256] fp32  (unchanged from R1)
// ---------------------------------------------------------------------------
#define GEMM_ROWS 32
__global__ __launch_bounds__(256) void k_gemm(const float* __restrict__ feat,
                                              const float* __restrict__ Wsum,
                                              float* __restrict__ h) {
    __shared__ float sfeat[GEMM_ROWS][D];
    const int row0 = blockIdx.x * GEMM_ROWS;
    const int t = threadIdx.x;

    const float4* feat4 = (const float4*)feat;
    float4* sfeat4 = (float4*)&sfeat[0][0];
#pragma unroll
    for (int i = 0; i < 8; ++i) {
        int idx = i * 256 + t;
        int rr = idx >> 6;
        int cc = idx & 63;
        int row = row0 + rr;
        float4 v = make_float4(0.f, 0.f, 0.f, 0.f);
        if (row < N_NODES) v = feat4[(size_t)row * 64 + cc];
        sfeat4[idx] = v;
    }
    __syncthreads();

    const int c = t & 63;
    const int g = t >> 6;
    float4 acc[8];
#pragma unroll
    for (int rr = 0; rr < 8; ++rr) acc[rr] = make_float4(0.f, 0.f, 0.f, 0.f);

    const float4* W4 = (const float4*)Wsum;
#pragma unroll 4
    for (int k = 0; k < D; ++k) {
        float4 wv = W4[k * 64 + c];
#pragma unroll
        for (int rr = 0; rr < 8; ++rr) {
            float f = sfeat[g * 8 + rr][k];
            acc[rr].x = fmaf(f, wv.x, acc[rr].x);
            acc[rr].y = fmaf(f, wv.y, acc[rr].y);
            acc[rr].z = fmaf(f, wv.z, acc[rr].z);
            acc[rr].w = fmaf(f, wv.w, acc[rr].w);
        }
    }

    float4* h4 = (float4*)h;
#pragma unroll
    for (int rr = 0; rr < 8; ++rr) {
        int row = row0 + g * 8 + rr;
        if (row < N_NODES) h4[(size_t)row * 64 + c] = acc[rr];
    }
}

// ---------------------------------------------------------------------------
// Kernel: fused gather + mean-of-means + ReLU + LayerNorm.
// One wave per node (lane holds float4 = 4 cols). No atomics.
// off[] holds bucket ENDs (post-fill); start = end - deg.
// ---------------------------------------------------------------------------
__global__ __launch_bounds__(256) void k_gather(const float* __restrict__ h,
                                                const int* __restrict__ eidx,
                                                const int* __restrict__ off,
                                                const int* __restrict__ deg,
                                                const float* __restrict__ gamma,
                                                const float* __restrict__ beta,
                                                float* __restrict__ out) {
    int node = blockIdx.x * 4 + (threadIdx.x >> 6);
    if (node >= N_NODES) return;
    int lane = threadIdx.x & 63;
    const float4* h4 = (const float4*)h;

    float4 acc = make_float4(0.f, 0.f, 0.f, 0.f);
#pragma unroll
    for (int r = 0; r < 3; ++r) {
        int idx = r * N_NODES + node;
        int dg = deg[idx];
        int end = off[idx];
        int start = end - dg;
        float w = 1.0f / (3.0f * (float)(dg > 1 ? dg : 1));
        float4 racc = make_float4(0.f, 0.f, 0.f, 0.f);
        for (int k = start; k < end; ++k) {
            int s = eidx[k];                       // wave-uniform
            float4 v = h4[(size_t)s * 64 + lane];  // coalesced 1 KB row
            racc.x += v.x; racc.y += v.y; racc.z += v.z; racc.w += v.w;
        }
        acc.x = fmaf(racc.x, w, acc.x);
        acc.y = fmaf(racc.y, w, acc.y);
        acc.z = fmaf(racc.z, w, acc.z);
        acc.w = fmaf(racc.w, w, acc.w);
    }

    // ReLU
    acc.x = fmaxf(acc.x, 0.f);
    acc.y = fmaxf(acc.y, 0.f);
    acc.z = fmaxf(acc.z, 0.f);
    acc.w = fmaxf(acc.w, 0.f);

    // LayerNorm over the 256 cols (64-lane shuffle reduction)
    float s  = acc.x + acc.y + acc.z + acc.w;
    float ss = acc.x * acc.x + acc.y * acc.y + acc.z * acc.z + acc.w * acc.w;
#pragma unroll
    for (int o2 = 32; o2 > 0; o2 >>= 1) {
        s  += __shfl_xor(s, o2, 64);
        ss += __shfl_xor(ss, o2, 64);
    }
    float mean = s * (1.0f / D);
    float var  = ss * (1.0f / D) - mean * mean;
    float inv  = rsqrtf(var + LN_EPS);

    float4 gm = ((const float4*)gamma)[lane];
    float4 bt = ((const float4*)beta)[lane];
    float4 rv;
    rv.x = (acc.x - mean) * inv * gm.x + bt.x;
    rv.y = (acc.y - mean) * inv * gm.y + bt.y;
    rv.z = (acc.z - mean) * inv * gm.z + bt.z;
    rv.w = (acc.w - mean) * inv * gm.w + bt.w;
    ((float4*)out)[(size_t)node * 64 + lane] = rv;
}

// ---------------------------------------------------------------------------
extern "C" void kernel_launch(void* const* d_in, const int* in_sizes, int n_in,
                              void* d_out, int out_size, void* d_ws, size_t ws_size,
                              hipStream_t stream) {
    const float* feat  = (const float*)d_in[0];
    const float* W0    = (const float*)d_in[1];
    const float* W1    = (const float*)d_in[2];
    const float* W2    = (const float*)d_in[3];
    // d_in[4..6] = a0,a1,a2: unused — softmax of singletons makes w == 1/3 exactly
    const float* gamma = (const float*)d_in[7];
    const float* beta  = (const float*)d_in[8];
    const int* src0 = (const int*)d_in[9];
    const int* dst0 = (const int*)d_in[10];
    const int* src1 = (const int*)d_in[11];
    const int* dst1 = (const int*)d_in[12];
    const int* src2 = (const int*)d_in[13];
    const int* dst2 = (const int*)d_in[14];
    float* out = (float*)d_out;

    // workspace layout (ints/floats, all 16B-aligned):
    // Wsum [64K f] | h [12.8M f] | deg [150K i] | off [150K i] | bsum [256 i]
    // | eidx [1.2M i]   total ~57.5 MB
    float* Wsum = (float*)d_ws;
    float* h    = Wsum + D * D;
    int*   deg  = (int*)(h + (size_t)N_NODES * D);
    int*   off  = deg + SCAN_N;
    int*   bsum = off + SCAN_N;
    int*   eidx = bsum + 256;

    hipMemsetAsync(deg, 0, SCAN_N * sizeof(int), stream);

    k_deg<<<(3 * E_EDGES + 255) / 256, 256, 0, stream>>>(dst0, dst1, dst2, deg);
    k_scan1<<<SCAN_NB, 256, 0, stream>>>(deg, off, bsum);
    k_scan2<<<1, 256, 0, stream>>>(bsum);
    k_scan3<<<(SCAN_N + 255) / 256, 256, 0, stream>>>(off, bsum);
    k_fill<<<(3 * E_EDGES + 255) / 256, 256, 0, stream>>>(src0, dst0, src1, dst1,
                                                          src2, dst2, off, eidx);
    k_wsum<<<(D * D + 255) / 256, 256, 0, stream>>>(W0, W1, W2, Wsum);
    k_gemm<<<(N_NODES + GEMM_ROWS - 1) / GEMM_ROWS, 256, 0, stream>>>(feat, Wsum, h);
    k_gather<<<(N_NODES + 3) / 4, 256, 0, stream>>>(h, eidx, off, deg,
                                                    gamma, beta, out);
}

// Round 3
// 471.575 us; speedup vs baseline: 9.0067x; 1.0827x over previous
//
#include <hip/hip_runtime.h>

#define N_NODES 50000
#define D       256
#define E_EDGES 400000
#define LN_EPS  1e-5f

#define SCAN_N  (3 * N_NODES)                       // 150000
#define SCAN_B  1024
#define SCAN_NB ((SCAN_N + SCAN_B - 1) / SCAN_B)    // 147

typedef __attribute__((ext_vector_type(8))) short bf16x8;
typedef __attribute__((ext_vector_type(4))) float f32x4;

__device__ __forceinline__ unsigned short f2bf(float f) {
    unsigned int x = __float_as_uint(f);
    x += 0x7fffu + ((x >> 16) & 1u);     // RNE
    return (unsigned short)(x >> 16);
}

// ---------------------------------------------------------------------------
// Wt[n][k] = bf16((W0[k][n]+W1[k][n]+W2[k][n])/3)  — transposed for MFMA B.
// (softmax of size-1 tensors == 1; softmax([1,1,1]) == exactly 1/3 each)
// ---------------------------------------------------------------------------
__global__ __launch_bounds__(256) void k_wsumT(const float* __restrict__ W0,
                                               const float* __restrict__ W1,
                                               const float* __restrict__ W2,
                                               unsigned short* __restrict__ Wt) {
    int i = blockIdx.x * 256 + threadIdx.x;      // i = n*256 + k
    if (i >= D * D) return;
    int n = i >> 8, k = i & 255;
    float v = (W0[k * D + n] + W1[k * D + n] + W2[k * D + n]) * (1.0f / 3.0f);
    Wt[i] = f2bf(v);
}

// ---------------------------------------------------------------------------
// Per-relation degree counts (int atomics)
// ---------------------------------------------------------------------------
__global__ __launch_bounds__(256) void k_deg(const int* __restrict__ dst0,
                                             const int* __restrict__ dst1,
                                             const int* __restrict__ dst2,
                                             int* __restrict__ deg) {
    int i = blockIdx.x * 256 + threadIdx.x;
    if (i >= 3 * E_EDGES) return;
    int r = i / E_EDGES;
    int j = i - r * E_EDGES;
    const int* d = (r == 0) ? dst0 : (r == 1) ? dst1 : dst2;
    atomicAdd(&deg[r * N_NODES + d[j]], 1);
}

// ---------------------------------------------------------------------------
// Exclusive prefix sum of deg[SCAN_N] -> off[SCAN_N]  (3 kernels)
// ---------------------------------------------------------------------------
__global__ __launch_bounds__(256) void k_scan1(const int* __restrict__ deg,
                                               int* __restrict__ off,
                                               int* __restrict__ bsum) {
    __shared__ int wsum[4];
    const int t = threadIdx.x;
    const int base = blockIdx.x * SCAN_B + t * 4;
    int4 v = make_int4(0, 0, 0, 0);
    if (base < SCAN_N) v = *(const int4*)(deg + base);
    const int s1 = v.x + v.y;
    const int s2 = s1 + v.z;
    const int s3 = s2 + v.w;
    const int lane = t & 63;
    int x = s3;
#pragma unroll
    for (int o2 = 1; o2 < 64; o2 <<= 1) {
        int y = __shfl_up(x, o2, 64);
        if (lane >= o2) x += y;
    }
    if (lane == 63) wsum[t >> 6] = x;
    const int texcl = x - s3;
    __syncthreads();
    int wbase = 0;
#pragma unroll
    for (int wi = 0; wi < 4; ++wi)
        if (wi < (t >> 6)) wbase += wsum[wi];
    const int ex = wbase + texcl;
    if (base < SCAN_N) {
        int4 o4;
        o4.x = ex; o4.y = ex + v.x; o4.z = ex + s1; o4.w = ex + s2;
        *(int4*)(off + base) = o4;
    }
    if (t == 0) bsum[blockIdx.x] = wsum[0] + wsum[1] + wsum[2] + wsum[3];
}

__global__ __launch_bounds__(256) void k_scan2(int* __restrict__ bsum) {
    __shared__ int wsum[4];
    const int t = threadIdx.x;
    const int v = (t < SCAN_NB) ? bsum[t] : 0;
    const int lane = t & 63;
    int x = v;
#pragma unroll
    for (int o2 = 1; o2 < 64; o2 <<= 1) {
        int y = __shfl_up(x, o2, 64);
        if (lane >= o2) x += y;
    }
    if (lane == 63) wsum[t >> 6] = x;
    __syncthreads();
    int wbase = 0;
#pragma unroll
    for (int wi = 0; wi < 4; ++wi)
        if (wi < (t >> 6)) wbase += wsum[wi];
    if (t < SCAN_NB) bsum[t] = wbase + x - v;
}

__global__ __launch_bounds__(256) void k_scan3(int* __restrict__ off,
                                               const int* __restrict__ bsum) {
    int i = blockIdx.x * 256 + threadIdx.x;
    if (i < SCAN_N) off[i] += bsum[i >> 10];
}

// ---------------------------------------------------------------------------
// Bucket fill: pos = off[bucket]++; eidx[pos] = src. off ends at bucket END.
// ---------------------------------------------------------------------------
__global__ __launch_bounds__(256) void k_fill(const int* __restrict__ src0,
                                              const int* __restrict__ dst0,
                                              const int* __restrict__ src1,
                                              const int* __restrict__ dst1,
                                              const int* __restrict__ src2,
                                              const int* __restrict__ dst2,
                                              int* __restrict__ off,
                                              int* __restrict__ eidx) {
    int i = blockIdx.x * 256 + threadIdx.x;
    if (i >= 3 * E_EDGES) return;
    int r = i / E_EDGES;
    int j = i - r * E_EDGES;
    const int* sp = (r == 0) ? src0 : (r == 1) ? src1 : src2;
    const int* dp = (r == 0) ? dst0 : (r == 1) ? dst1 : dst2;
    int pos = atomicAdd(&off[r * N_NODES + dp[j]], 1);
    eidx[pos] = sp[j];
}

// ---------------------------------------------------------------------------
// MFMA GEMM: h_bf16 = bf16(feat) @ Wt^T   ([N,256] x [256,256])
// Block: 256 thr (4 waves), 64 rows, full K=256 staged in LDS as bf16.
// Wave w: rows [w*16, w*16+16), 16 col-tiles of 16, 8 K-steps of 32.
// A-frag: lane l holds A[m=l&15][k=(l>>4)*8+j] -> contiguous 16B LDS read.
// B-frag: lane l holds B[k][n=l&15], read as Wt[n][k..k+8] contiguous 16B.
// C/D: col=lane&15, row=(lane>>4)*4+reg  (verified layout).
// Epilogue: acc -> LDS (own 16-row slice) -> coalesced 16B bf16 stores.
// ---------------------------------------------------------------------------
#define GB_ROWS 64
__global__ __launch_bounds__(256) void k_gemm(const float* __restrict__ feat,
                                              const unsigned short* __restrict__ Wt,
                                              unsigned short* __restrict__ h) {
    __shared__ unsigned short sA[GB_ROWS][D + 8];   // +8 bf16 pad = 16B
    const int t = threadIdx.x;
    const int row0 = blockIdx.x * GB_ROWS;

    // stage feat (fp32) -> sA (bf16): 64 rows x 256 cols, 16 float4 per thread
    const float4* feat4 = (const float4*)feat;
#pragma unroll
    for (int i = 0; i < 16; ++i) {
        int c = i * 256 + t;            // float4 chunk id in 64x64-f4 tile
        int r = c >> 6, c4 = c & 63;
        float4 v = make_float4(0.f, 0.f, 0.f, 0.f);
        if (row0 + r < N_NODES) v = feat4[(size_t)(row0 + r) * 64 + c4];
        ushort4 p;
        p.x = f2bf(v.x); p.y = f2bf(v.y); p.z = f2bf(v.z); p.w = f2bf(v.w);
        *(ushort4*)&sA[r][c4 * 4] = p;
    }
    __syncthreads();

    const int lane = t & 63;
    const int w    = t >> 6;
    const int lr   = lane & 15;        // m (A) / n (B) / col (C)
    const int lq   = lane >> 4;        // quad

    f32x4 acc[16];
#pragma unroll
    for (int tt = 0; tt < 16; ++tt) acc[tt] = (f32x4){0.f, 0.f, 0.f, 0.f};

    const bf16x8* WtV = (const bf16x8*)Wt;          // 32 chunks per 256-col row
#pragma unroll
    for (int ks = 0; ks < 8; ++ks) {
        bf16x8 af = *(const bf16x8*)&sA[w * 16 + lr][ks * 32 + lq * 8];
#pragma unroll
        for (int tt = 0; tt < 16; ++tt) {
            bf16x8 bfr = WtV[(tt * 16 + lr) * 32 + ks * 4 + lq];
            acc[tt] = __builtin_amdgcn_mfma_f32_16x16x32_bf16(af, bfr, acc[tt], 0, 0, 0);
        }
    }

    // epilogue: scatter acc into own LDS slice as bf16, then coalesced store
#pragma unroll
    for (int tt = 0; tt < 16; ++tt) {
#pragma unroll
        for (int j = 0; j < 4; ++j)
            sA[w * 16 + lq * 4 + j][tt * 16 + lr] = f2bf(acc[tt][j]);
    }
    __syncthreads();

#pragma unroll
    for (int i = 0; i < 8; ++i) {
        int c = i * 256 + t;            // ushort8 chunk id: 64 rows x 32 chunks
        int r = c >> 5, cc = c & 31;
        if (row0 + r < N_NODES) {
            uint4 v = *(const uint4*)&sA[r][cc * 8];
            *(uint4*)(h + (size_t)(row0 + r) * D + cc * 8) = v;
        }
    }
}

// ---------------------------------------------------------------------------
// Fused gather(mean of 3 relation-means) + ReLU + LayerNorm.  h is bf16.
// One wave per node; lane holds 4 cols (8 B bf16 load per lane per edge).
// ---------------------------------------------------------------------------
__global__ __launch_bounds__(256) void k_gather(const unsigned short* __restrict__ h,
                                                const int* __restrict__ eidx,
                                                const int* __restrict__ off,
                                                const int* __restrict__ deg,
                                                const float* __restrict__ gamma,
                                                const float* __restrict__ beta,
                                                float* __restrict__ out) {
    int node = blockIdx.x * 4 + (threadIdx.x >> 6);
    if (node >= N_NODES) return;
    int lane = threadIdx.x & 63;
    const uint2* h2 = (const uint2*)h;             // 64 uint2 per 256-col row

    float4 acc = make_float4(0.f, 0.f, 0.f, 0.f);
#pragma unroll
    for (int r = 0; r < 3; ++r) {
        int idx = r * N_NODES + node;
        int dg = deg[idx];
        int end = off[idx];
        int start = end - dg;
        float wgt = 1.0f / (3.0f * (float)(dg > 1 ? dg : 1));
        float4 racc = make_float4(0.f, 0.f, 0.f, 0.f);
        for (int k = start; k < end; ++k) {
            int s = eidx[k];                        // wave-uniform
            uint2 u = h2[(size_t)s * 64 + lane];    // coalesced 512B row
            racc.x += __uint_as_float(u.x << 16);
            racc.y += __uint_as_float(u.x & 0xffff0000u);
            racc.z += __uint_as_float(u.y << 16);
            racc.w += __uint_as_float(u.y & 0xffff0000u);
        }
        acc.x = fmaf(racc.x, wgt, acc.x);
        acc.y = fmaf(racc.y, wgt, acc.y);
        acc.z = fmaf(racc.z, wgt, acc.z);
        acc.w = fmaf(racc.w, wgt, acc.w);
    }

    acc.x = fmaxf(acc.x, 0.f);
    acc.y = fmaxf(acc.y, 0.f);
    acc.z = fmaxf(acc.z, 0.f);
    acc.w = fmaxf(acc.w, 0.f);

    float s  = acc.x + acc.y + acc.z + acc.w;
    float ss = acc.x * acc.x + acc.y * acc.y + acc.z * acc.z + acc.w * acc.w;
#pragma unroll
    for (int o2 = 32; o2 > 0; o2 >>= 1) {
        s  += __shfl_xor(s, o2, 64);
        ss += __shfl_xor(ss, o2, 64);
    }
    float mean = s * (1.0f / D);
    float var  = ss * (1.0f / D) - mean * mean;
    float inv  = rsqrtf(var + LN_EPS);

    float4 gm = ((const float4*)gamma)[lane];
    float4 bt = ((const float4*)beta)[lane];
    float4 rv;
    rv.x = (acc.x - mean) * inv * gm.x + bt.x;
    rv.y = (acc.y - mean) * inv * gm.y + bt.y;
    rv.z = (acc.z - mean) * inv * gm.z + bt.z;
    rv.w = (acc.w - mean) * inv * gm.w + bt.w;
    ((float4*)out)[(size_t)node * 64 + lane] = rv;
}

// ---------------------------------------------------------------------------
extern "C" void kernel_launch(void* const* d_in, const int* in_sizes, int n_in,
                              void* d_out, int out_size, void* d_ws, size_t ws_size,
                              hipStream_t stream) {
    const float* feat  = (const float*)d_in[0];
    const float* W0    = (const float*)d_in[1];
    const float* W1    = (const float*)d_in[2];
    const float* W2    = (const float*)d_in[3];
    // d_in[4..6] = a0,a1,a2: unused — attention weights are exactly 1/3
    const float* gamma = (const float*)d_in[7];
    const float* beta  = (const float*)d_in[8];
    const int* src0 = (const int*)d_in[9];
    const int* dst0 = (const int*)d_in[10];
    const int* src1 = (const int*)d_in[11];
    const int* dst1 = (const int*)d_in[12];
    const int* src2 = (const int*)d_in[13];
    const int* dst2 = (const int*)d_in[14];
    float* out = (float*)d_out;

    // workspace: h bf16 [12.8M us] | Wt bf16 [64K us] | deg|off|bsum|eidx ints
    unsigned short* h  = (unsigned short*)d_ws;
    unsigned short* Wt = h + (size_t)N_NODES * D;
    int* deg  = (int*)(Wt + D * D);
    int* off  = deg + SCAN_N;
    int* bsum = off + SCAN_N;
    int* eidx = bsum + 256;

    hipMemsetAsync(deg, 0, SCAN_N * sizeof(int), stream);

    k_deg<<<(3 * E_EDGES + 255) / 256, 256, 0, stream>>>(dst0, dst1, dst2, deg);
    k_scan1<<<SCAN_NB, 256, 0, stream>>>(deg, off, bsum);
    k_scan2<<<1, 256, 0, stream>>>(bsum);
    k_scan3<<<(SCAN_N + 255) / 256, 256, 0, stream>>>(off, bsum);
    k_fill<<<(3 * E_EDGES + 255) / 256, 256, 0, stream>>>(src0, dst0, src1, dst1,
                                                          src2, dst2, off, eidx);
    k_wsumT<<<(D * D + 255) / 256, 256, 0, stream>>>(W0, W1, W2, Wt);
    k_gemm<<<(N_NODES + GB_ROWS - 1) / GB_ROWS, 256, 0, stream>>>(feat, Wt, h);
    k_gather<<<(N_NODES + 3) / 4, 256, 0, stream>>>(h, eidx, off, deg,
                                                    gamma, beta, out);
}

// Round 4
// 409.114 us; speedup vs baseline: 10.3818x; 1.1527x over previous
//
#include <hip/hip_runtime.h>

#define N_NODES 50000
#define D       256
#define E_EDGES 400000
#define LN_EPS  1e-5f

#define SCAN_N  (3 * N_NODES)                       // 150000
#define SCAN_B  1024
#define SCAN_NB ((SCAN_N + SCAN_B - 1) / SCAN_B)    // 147

typedef __attribute__((ext_vector_type(8))) short bf16x8;
typedef __attribute__((ext_vector_type(4))) float f32x4;

__device__ __forceinline__ unsigned short f2bf(float f) {
    unsigned int x = __float_as_uint(f);
    x += 0x7fffu + ((x >> 16) & 1u);     // RNE
    return (unsigned short)(x >> 16);
}

// ---------------------------------------------------------------------------
// Wt[n][k] = bf16((W0[k][n]+W1[k][n]+W2[k][n])/3)  — transposed for MFMA B.
// (softmax of size-1 tensors == 1; softmax([1,1,1]) == exactly 1/3 each)
// ---------------------------------------------------------------------------
__global__ __launch_bounds__(256) void k_wsumT(const float* __restrict__ W0,
                                               const float* __restrict__ W1,
                                               const float* __restrict__ W2,
                                               unsigned short* __restrict__ Wt) {
    int i = blockIdx.x * 256 + threadIdx.x;      // i = n*256 + k
    if (i >= D * D) return;
    int n = i >> 8, k = i & 255;
    float v = (W0[k * D + n] + W1[k * D + n] + W2[k * D + n]) * (1.0f / 3.0f);
    Wt[i] = f2bf(v);
}

// ---------------------------------------------------------------------------
// Per-relation degree counts (int atomics)
// ---------------------------------------------------------------------------
__global__ __launch_bounds__(256) void k_deg(const int* __restrict__ dst0,
                                             const int* __restrict__ dst1,
                                             const int* __restrict__ dst2,
                                             int* __restrict__ deg) {
    int i = blockIdx.x * 256 + threadIdx.x;
    if (i >= 3 * E_EDGES) return;
    int r = i / E_EDGES;
    int j = i - r * E_EDGES;
    const int* d = (r == 0) ? dst0 : (r == 1) ? dst1 : dst2;
    atomicAdd(&deg[r * N_NODES + d[j]], 1);
}

// ---------------------------------------------------------------------------
// Prefix sum of deg[SCAN_N]: off = block-LOCAL exclusive scan, bsum = per-
// block bases (scan2 turns sums into exclusive bases). Global offset =
// off[i] + bsum[i>>10], applied on the fly in k_fill / k_gather (no scan3).
// ---------------------------------------------------------------------------
__global__ __launch_bounds__(256) void k_scan1(const int* __restrict__ deg,
                                               int* __restrict__ off,
                                               int* __restrict__ bsum) {
    __shared__ int wsum[4];
    const int t = threadIdx.x;
    const int base = blockIdx.x * SCAN_B + t * 4;
    int4 v = make_int4(0, 0, 0, 0);
    if (base < SCAN_N) v = *(const int4*)(deg + base);
    const int s1 = v.x + v.y;
    const int s2 = s1 + v.z;
    const int s3 = s2 + v.w;
    const int lane = t & 63;
    int x = s3;
#pragma unroll
    for (int o2 = 1; o2 < 64; o2 <<= 1) {
        int y = __shfl_up(x, o2, 64);
        if (lane >= o2) x += y;
    }
    if (lane == 63) wsum[t >> 6] = x;
    const int texcl = x - s3;
    __syncthreads();
    int wbase = 0;
#pragma unroll
    for (int wi = 0; wi < 4; ++wi)
        if (wi < (t >> 6)) wbase += wsum[wi];
    const int ex = wbase + texcl;
    if (base < SCAN_N) {
        int4 o4;
        o4.x = ex; o4.y = ex + v.x; o4.z = ex + s1; o4.w = ex + s2;
        *(int4*)(off + base) = o4;
    }
    if (t == 0) bsum[blockIdx.x] = wsum[0] + wsum[1] + wsum[2] + wsum[3];
}

__global__ __launch_bounds__(256) void k_scan2(int* __restrict__ bsum) {
    __shared__ int wsum[4];
    const int t = threadIdx.x;
    const int v = (t < SCAN_NB) ? bsum[t] : 0;
    const int lane = t & 63;
    int x = v;
#pragma unroll
    for (int o2 = 1; o2 < 64; o2 <<= 1) {
        int y = __shfl_up(x, o2, 64);
        if (lane >= o2) x += y;
    }
    if (lane == 63) wsum[t >> 6] = x;
    __syncthreads();
    int wbase = 0;
#pragma unroll
    for (int wi = 0; wi < 4; ++wi)
        if (wi < (t >> 6)) wbase += wsum[wi];
    if (t < SCAN_NB) bsum[t] = wbase + x - v;
}

// ---------------------------------------------------------------------------
// Bucket fill: pos = (off_local[bucket]++) + bsum[block]; eidx[pos] = src.
// After this kernel off[bucket] == local END (global end = +bsum).
// ---------------------------------------------------------------------------
__global__ __launch_bounds__(256) void k_fill(const int* __restrict__ src0,
                                              const int* __restrict__ dst0,
                                              const int* __restrict__ src1,
                                              const int* __restrict__ dst1,
                                              const int* __restrict__ src2,
                                              const int* __restrict__ dst2,
                                              int* __restrict__ off,
                                              const int* __restrict__ bsum,
                                              int* __restrict__ eidx) {
    int i = blockIdx.x * 256 + threadIdx.x;
    if (i >= 3 * E_EDGES) return;
    int r = i / E_EDGES;
    int j = i - r * E_EDGES;
    const int* sp = (r == 0) ? src0 : (r == 1) ? src1 : src2;
    const int* dp = (r == 0) ? dst0 : (r == 1) ? dst1 : dst2;
    int idx = r * N_NODES + dp[j];
    int pos = atomicAdd(&off[idx], 1) + bsum[idx >> 10];
    eidx[pos] = sp[j];
}

// ---------------------------------------------------------------------------
// MFMA GEMM: h_bf16 = bf16(feat) @ Wt^T   (unchanged from R3)
// ---------------------------------------------------------------------------
#define GB_ROWS 64
__global__ __launch_bounds__(256) void k_gemm(const float* __restrict__ feat,
                                              const unsigned short* __restrict__ Wt,
                                              unsigned short* __restrict__ h) {
    __shared__ unsigned short sA[GB_ROWS][D + 8];   // +8 bf16 pad = 16B
    const int t = threadIdx.x;
    const int row0 = blockIdx.x * GB_ROWS;

    const float4* feat4 = (const float4*)feat;
#pragma unroll
    for (int i = 0; i < 16; ++i) {
        int c = i * 256 + t;
        int r = c >> 6, c4 = c & 63;
        float4 v = make_float4(0.f, 0.f, 0.f, 0.f);
        if (row0 + r < N_NODES) v = feat4[(size_t)(row0 + r) * 64 + c4];
        ushort4 p;
        p.x = f2bf(v.x); p.y = f2bf(v.y); p.z = f2bf(v.z); p.w = f2bf(v.w);
        *(ushort4*)&sA[r][c4 * 4] = p;
    }
    __syncthreads();

    const int lane = t & 63;
    const int w    = t >> 6;
    const int lr   = lane & 15;
    const int lq   = lane >> 4;

    f32x4 acc[16];
#pragma unroll
    for (int tt = 0; tt < 16; ++tt) acc[tt] = (f32x4){0.f, 0.f, 0.f, 0.f};

    const bf16x8* WtV = (const bf16x8*)Wt;
#pragma unroll
    for (int ks = 0; ks < 8; ++ks) {
        bf16x8 af = *(const bf16x8*)&sA[w * 16 + lr][ks * 32 + lq * 8];
#pragma unroll
        for (int tt = 0; tt < 16; ++tt) {
            bf16x8 bfr = WtV[(tt * 16 + lr) * 32 + ks * 4 + lq];
            acc[tt] = __builtin_amdgcn_mfma_f32_16x16x32_bf16(af, bfr, acc[tt], 0, 0, 0);
        }
    }

#pragma unroll
    for (int tt = 0; tt < 16; ++tt) {
#pragma unroll
        for (int j = 0; j < 4; ++j)
            sA[w * 16 + lq * 4 + j][tt * 16 + lr] = f2bf(acc[tt][j]);
    }
    __syncthreads();

#pragma unroll
    for (int i = 0; i < 8; ++i) {
        int c = i * 256 + t;
        int r = c >> 5, cc = c & 31;
        if (row0 + r < N_NODES) {
            uint4 v = *(const uint4*)&sA[r][cc * 8];
            *(uint4*)(h + (size_t)(row0 + r) * D + cc * 8) = v;
        }
    }
}

// ---------------------------------------------------------------------------
// Fused gather + ReLU + LayerNorm, 4-deep edge unroll for MLP.
// One wave per node; lane holds 4 cols (8 B bf16 per lane per edge row).
// ---------------------------------------------------------------------------
__device__ __forceinline__ void bf2x4_acc(uint2 u, float4& a) {
    a.x += __uint_as_float(u.x << 16);
    a.y += __uint_as_float(u.x & 0xffff0000u);
    a.z += __uint_as_float(u.y << 16);
    a.w += __uint_as_float(u.y & 0xffff0000u);
}

__global__ __launch_bounds__(256) void k_gather(const unsigned short* __restrict__ h,
                                                const int* __restrict__ eidx,
                                                const int* __restrict__ off,
                                                const int* __restrict__ bsum,
                                                const int* __restrict__ deg,
                                                const float* __restrict__ gamma,
                                                const float* __restrict__ beta,
                                                float* __restrict__ out) {
    int node = blockIdx.x * 4 + (threadIdx.x >> 6);
    if (node >= N_NODES) return;
    int lane = threadIdx.x & 63;
    const uint2* h2 = (const uint2*)h;

    float4 acc = make_float4(0.f, 0.f, 0.f, 0.f);
#pragma unroll
    for (int r = 0; r < 3; ++r) {
        int idx = r * N_NODES + node;
        int dg = deg[idx];
        int end = off[idx] + bsum[idx >> 10];   // off holds local end post-fill
        int start = end - dg;
        float wgt = 1.0f / (3.0f * (float)(dg > 1 ? dg : 1));
        float4 racc = make_float4(0.f, 0.f, 0.f, 0.f);

        int k = start;
        for (; k + 4 <= end; k += 4) {
            // 4 independent index loads, then 4 independent row loads: MLP=4
            int s0 = eidx[k + 0];
            int s1 = eidx[k + 1];
            int s2 = eidx[k + 2];
            int s3 = eidx[k + 3];
            uint2 u0 = h2[(size_t)s0 * 64 + lane];
            uint2 u1 = h2[(size_t)s1 * 64 + lane];
            uint2 u2 = h2[(size_t)s2 * 64 + lane];
            uint2 u3 = h2[(size_t)s3 * 64 + lane];
            bf2x4_acc(u0, racc);
            bf2x4_acc(u1, racc);
            bf2x4_acc(u2, racc);
            bf2x4_acc(u3, racc);
        }
        for (; k < end; ++k) {
            int s = eidx[k];
            uint2 u = h2[(size_t)s * 64 + lane];
            bf2x4_acc(u, racc);
        }
        acc.x = fmaf(racc.x, wgt, acc.x);
        acc.y = fmaf(racc.y, wgt, acc.y);
        acc.z = fmaf(racc.z, wgt, acc.z);
        acc.w = fmaf(racc.w, wgt, acc.w);
    }

    acc.x = fmaxf(acc.x, 0.f);
    acc.y = fmaxf(acc.y, 0.f);
    acc.z = fmaxf(acc.z, 0.f);
    acc.w = fmaxf(acc.w, 0.f);

    float s  = acc.x + acc.y + acc.z + acc.w;
    float ss = acc.x * acc.x + acc.y * acc.y + acc.z * acc.z + acc.w * acc.w;
#pragma unroll
    for (int o2 = 32; o2 > 0; o2 >>= 1) {
        s  += __shfl_xor(s, o2, 64);
        ss += __shfl_xor(ss, o2, 64);
    }
    float mean = s * (1.0f / D);
    float var  = ss * (1.0f / D) - mean * mean;
    float inv  = rsqrtf(var + LN_EPS);

    float4 gm = ((const float4*)gamma)[lane];
    float4 bt = ((const float4*)beta)[lane];
    float4 rv;
    rv.x = (acc.x - mean) * inv * gm.x + bt.x;
    rv.y = (acc.y - mean) * inv * gm.y + bt.y;
    rv.z = (acc.z - mean) * inv * gm.z + bt.z;
    rv.w = (acc.w - mean) * inv * gm.w + bt.w;
    ((float4*)out)[(size_t)node * 64 + lane] = rv;
}

// ---------------------------------------------------------------------------
extern "C" void kernel_launch(void* const* d_in, const int* in_sizes, int n_in,
                              void* d_out, int out_size, void* d_ws, size_t ws_size,
                              hipStream_t stream) {
    const float* feat  = (const float*)d_in[0];
    const float* W0    = (const float*)d_in[1];
    const float* W1    = (const float*)d_in[2];
    const float* W2    = (const float*)d_in[3];
    // d_in[4..6] = a0,a1,a2: unused — attention weights are exactly 1/3
    const float* gamma = (const float*)d_in[7];
    const float* beta  = (const float*)d_in[8];
    const int* src0 = (const int*)d_in[9];
    const int* dst0 = (const int*)d_in[10];
    const int* src1 = (const int*)d_in[11];
    const int* dst1 = (const int*)d_in[12];
    const int* src2 = (const int*)d_in[13];
    const int* dst2 = (const int*)d_in[14];
    float* out = (float*)d_out;

    // workspace: h bf16 [12.8M us] | Wt bf16 [64K us] | deg|off|bsum|eidx ints
    unsigned short* h  = (unsigned short*)d_ws;
    unsigned short* Wt = h + (size_t)N_NODES * D;
    int* deg  = (int*)(Wt + D * D);
    int* off  = deg + SCAN_N;
    int* bsum = off + SCAN_N;
    int* eidx = bsum + 256;

    hipMemsetAsync(deg, 0, SCAN_N * sizeof(int), stream);

    k_deg<<<(3 * E_EDGES + 255) / 256, 256, 0, stream>>>(dst0, dst1, dst2, deg);
    k_scan1<<<SCAN_NB, 256, 0, stream>>>(deg, off, bsum);
    k_scan2<<<1, 256, 0, stream>>>(bsum);
    k_fill<<<(3 * E_EDGES + 255) / 256, 256, 0, stream>>>(src0, dst0, src1, dst1,
                                                          src2, dst2, off, bsum, eidx);
    k_wsumT<<<(D * D + 255) / 256, 256, 0, stream>>>(W0, W1, W2, Wt);
    k_gemm<<<(N_NODES + GB_ROWS - 1) / GB_ROWS, 256, 0, stream>>>(feat, Wt, h);
    k_gather<<<(N_NODES + 3) / 4, 256, 0, stream>>>(h, eidx, off, bsum, deg,
                                                    gamma, beta, out);
}

// Round 5
// 405.169 us; speedup vs baseline: 10.4829x; 1.0097x over previous
//
#include <hip/hip_runtime.h>

#define N_NODES 50000
#define D       256
#define E_EDGES 400000
#define LN_EPS  1e-5f

#define SCAN_N  (3 * N_NODES)                       // 150000
#define SCAN_B  1024
#define SCAN_NB ((SCAN_N + SCAN_B - 1) / SCAN_B)    // 147

typedef __attribute__((ext_vector_type(8))) short bf16x8;
typedef __attribute__((ext_vector_type(4))) float f32x4;

__device__ __forceinline__ unsigned short f2bf(float f) {
    unsigned int x = __float_as_uint(f);
    x += 0x7fffu + ((x >> 16) & 1u);     // RNE
    return (unsigned short)(x >> 16);
}

// ---------------------------------------------------------------------------
// Merged prep: blocks [0,256) build Wt (transposed bf16 (W0+W1+W2)/3);
// blocks [256, 256+4688) do per-relation degree counts.
// (softmax of size-1 tensors == 1; softmax([1,1,1]) == exactly 1/3 each)
// ---------------------------------------------------------------------------
#define DEG_NB ((3 * E_EDGES + 255) / 256)          // 4688
__global__ __launch_bounds__(256) void k_prep(const float* __restrict__ W0,
                                              const float* __restrict__ W1,
                                              const float* __restrict__ W2,
                                              unsigned short* __restrict__ Wt,
                                              const int* __restrict__ dst0,
                                              const int* __restrict__ dst1,
                                              const int* __restrict__ dst2,
                                              int* __restrict__ deg) {
    int b = blockIdx.x;
    if (b < 256) {
        int i = b * 256 + threadIdx.x;          // i = n*256 + k
        int n = i >> 8, k = i & 255;
        float v = (W0[k * D + n] + W1[k * D + n] + W2[k * D + n]) * (1.0f / 3.0f);
        Wt[i] = f2bf(v);
    } else {
        int i = (b - 256) * 256 + threadIdx.x;
        if (i >= 3 * E_EDGES) return;
        int r = i / E_EDGES;
        int j = i - r * E_EDGES;
        const int* d = (r == 0) ? dst0 : (r == 1) ? dst1 : dst2;
        atomicAdd(&deg[r * N_NODES + d[j]], 1);
    }
}

// ---------------------------------------------------------------------------
// Prefix sum of deg[SCAN_N]: off = block-LOCAL exclusive scan, bsum = per-
// block exclusive bases. Global offset = off[i] + bsum[i>>10] (no scan3).
// ---------------------------------------------------------------------------
__global__ __launch_bounds__(256) void k_scan1(const int* __restrict__ deg,
                                               int* __restrict__ off,
                                               int* __restrict__ bsum) {
    __shared__ int wsum[4];
    const int t = threadIdx.x;
    const int base = blockIdx.x * SCAN_B + t * 4;
    int4 v = make_int4(0, 0, 0, 0);
    if (base < SCAN_N) v = *(const int4*)(deg + base);
    const int s1 = v.x + v.y;
    const int s2 = s1 + v.z;
    const int s3 = s2 + v.w;
    const int lane = t & 63;
    int x = s3;
#pragma unroll
    for (int o2 = 1; o2 < 64; o2 <<= 1) {
        int y = __shfl_up(x, o2, 64);
        if (lane >= o2) x += y;
    }
    if (lane == 63) wsum[t >> 6] = x;
    const int texcl = x - s3;
    __syncthreads();
    int wbase = 0;
#pragma unroll
    for (int wi = 0; wi < 4; ++wi)
        if (wi < (t >> 6)) wbase += wsum[wi];
    const int ex = wbase + texcl;
    if (base < SCAN_N) {
        int4 o4;
        o4.x = ex; o4.y = ex + v.x; o4.z = ex + s1; o4.w = ex + s2;
        *(int4*)(off + base) = o4;
    }
    if (t == 0) bsum[blockIdx.x] = wsum[0] + wsum[1] + wsum[2] + wsum[3];
}

__global__ __launch_bounds__(256) void k_scan2(int* __restrict__ bsum) {
    __shared__ int wsum[4];
    const int t = threadIdx.x;
    const int v = (t < SCAN_NB) ? bsum[t] : 0;
    const int lane = t & 63;
    int x = v;
#pragma unroll
    for (int o2 = 1; o2 < 64; o2 <<= 1) {
        int y = __shfl_up(x, o2, 64);
        if (lane >= o2) x += y;
    }
    if (lane == 63) wsum[t >> 6] = x;
    __syncthreads();
    int wbase = 0;
#pragma unroll
    for (int wi = 0; wi < 4; ++wi)
        if (wi < (t >> 6)) wbase += wsum[wi];
    if (t < SCAN_NB) bsum[t] = wbase + x - v;
}

// ---------------------------------------------------------------------------
// Bucket fill: pos = (off_local[bucket]++) + bsum[block]; eidx[pos] = src.
// After this kernel off[bucket] == local END (global end = +bsum).
// ---------------------------------------------------------------------------
__global__ __launch_bounds__(256) void k_fill(const int* __restrict__ src0,
                                              const int* __restrict__ dst0,
                                              const int* __restrict__ src1,
                                              const int* __restrict__ dst1,
                                              const int* __restrict__ src2,
                                              const int* __restrict__ dst2,
                                              int* __restrict__ off,
                                              const int* __restrict__ bsum,
                                              int* __restrict__ eidx) {
    int i = blockIdx.x * 256 + threadIdx.x;
    if (i >= 3 * E_EDGES) return;
    int r = i / E_EDGES;
    int j = i - r * E_EDGES;
    const int* sp = (r == 0) ? src0 : (r == 1) ? src1 : src2;
    const int* dp = (r == 0) ? dst0 : (r == 1) ? dst1 : dst2;
    int idx = r * N_NODES + dp[j];
    int pos = atomicAdd(&off[idx], 1) + bsum[idx >> 10];
    eidx[pos] = sp[j];
}

// ---------------------------------------------------------------------------
// MFMA GEMM: h_bf16 = bf16(feat) @ Wt^T   ([N,256] x [256,256])
// 32-row / 128-thread (2-wave) blocks -> grid 1563 (~6 blocks/CU) for
// latency hiding. Per K-step: all 16 B-fragments batched into registers
// (16-deep VMEM MLP) before the 16 MFMAs.
// ---------------------------------------------------------------------------
#define GB_ROWS 32
__global__ __launch_bounds__(128, 3) void k_gemm(const float* __restrict__ feat,
                                                 const unsigned short* __restrict__ Wt,
                                                 unsigned short* __restrict__ h) {
    __shared__ unsigned short sA[GB_ROWS][D + 8];   // +8 bf16 pad = 16B
    const int t = threadIdx.x;
    const int row0 = blockIdx.x * GB_ROWS;

    // stage feat (fp32) -> sA (bf16): 32 rows x 64 float4 = 2048; 16/thread
    const float4* feat4 = (const float4*)feat;
#pragma unroll
    for (int i = 0; i < 16; ++i) {
        int c = i * 128 + t;
        int r = c >> 6, c4 = c & 63;
        float4 v = make_float4(0.f, 0.f, 0.f, 0.f);
        if (row0 + r < N_NODES) v = feat4[(size_t)(row0 + r) * 64 + c4];
        ushort4 p;
        p.x = f2bf(v.x); p.y = f2bf(v.y); p.z = f2bf(v.z); p.w = f2bf(v.w);
        *(ushort4*)&sA[r][c4 * 4] = p;
    }
    __syncthreads();

    const int lane = t & 63;
    const int w    = t >> 6;          // 0..1
    const int lr   = lane & 15;
    const int lq   = lane >> 4;

    f32x4 acc[16];
#pragma unroll
    for (int tt = 0; tt < 16; ++tt) acc[tt] = (f32x4){0.f, 0.f, 0.f, 0.f};

    const bf16x8* WtV = (const bf16x8*)Wt;
#pragma unroll
    for (int ks = 0; ks < 8; ++ks) {
        bf16x8 bfr[16];
#pragma unroll
        for (int tt = 0; tt < 16; ++tt)
            bfr[tt] = WtV[(tt * 16 + lr) * 32 + ks * 4 + lq];
        bf16x8 af = *(const bf16x8*)&sA[w * 16 + lr][ks * 32 + lq * 8];
#pragma unroll
        for (int tt = 0; tt < 16; ++tt)
            acc[tt] = __builtin_amdgcn_mfma_f32_16x16x32_bf16(af, bfr[tt], acc[tt], 0, 0, 0);
    }

    // epilogue: acc -> LDS slice as bf16 -> coalesced 16B stores
#pragma unroll
    for (int tt = 0; tt < 16; ++tt) {
#pragma unroll
        for (int j = 0; j < 4; ++j)
            sA[w * 16 + lq * 4 + j][tt * 16 + lr] = f2bf(acc[tt][j]);
    }
    __syncthreads();

#pragma unroll
    for (int i = 0; i < 8; ++i) {
        int c = i * 128 + t;            // 32 rows x 32 ushort8-chunks
        int r = c >> 5, cc = c & 31;
        if (row0 + r < N_NODES) {
            uint4 v = *(const uint4*)&sA[r][cc * 8];
            *(uint4*)(h + (size_t)(row0 + r) * D + cc * 8) = v;
        }
    }
}

// ---------------------------------------------------------------------------
// Fused gather + ReLU + LayerNorm, 8-deep edge unroll (mean deg = 8).
// One wave per node; lane holds 4 cols (8 B bf16 per lane per edge row).
// ---------------------------------------------------------------------------
__device__ __forceinline__ void bf2x4_acc(uint2 u, float4& a) {
    a.x += __uint_as_float(u.x << 16);
    a.y += __uint_as_float(u.x & 0xffff0000u);
    a.z += __uint_as_float(u.y << 16);
    a.w += __uint_as_float(u.y & 0xffff0000u);
}

__global__ __launch_bounds__(256) void k_gather(const unsigned short* __restrict__ h,
                                                const int* __restrict__ eidx,
                                                const int* __restrict__ off,
                                                const int* __restrict__ bsum,
                                                const int* __restrict__ deg,
                                                const float* __restrict__ gamma,
                                                const float* __restrict__ beta,
                                                float* __restrict__ out) {
    int node = blockIdx.x * 4 + (threadIdx.x >> 6);
    if (node >= N_NODES) return;
    int lane = threadIdx.x & 63;
    const uint2* h2 = (const uint2*)h;

    float4 acc = make_float4(0.f, 0.f, 0.f, 0.f);
#pragma unroll
    for (int r = 0; r < 3; ++r) {
        int idx = r * N_NODES + node;
        int dg = deg[idx];
        int end = off[idx] + bsum[idx >> 10];   // off holds local end post-fill
        int start = end - dg;
        float wgt = 1.0f / (3.0f * (float)(dg > 1 ? dg : 1));
        float4 racc = make_float4(0.f, 0.f, 0.f, 0.f);

        int k = start;
        for (; k + 8 <= end; k += 8) {
            int s[8];
#pragma unroll
            for (int u = 0; u < 8; ++u) s[u] = eidx[k + u];
            uint2 v[8];
#pragma unroll
            for (int u = 0; u < 8; ++u) v[u] = h2[(size_t)s[u] * 64 + lane];
#pragma unroll
            for (int u = 0; u < 8; ++u) bf2x4_acc(v[u], racc);
        }
        if (k + 4 <= end) {
            int s[4];
#pragma unroll
            for (int u = 0; u < 4; ++u) s[u] = eidx[k + u];
            uint2 v[4];
#pragma unroll
            for (int u = 0; u < 4; ++u) v[u] = h2[(size_t)s[u] * 64 + lane];
#pragma unroll
            for (int u = 0; u < 4; ++u) bf2x4_acc(v[u], racc);
            k += 4;
        }
        for (; k < end; ++k) {
            int s = eidx[k];
            uint2 u = h2[(size_t)s * 64 + lane];
            bf2x4_acc(u, racc);
        }
        acc.x = fmaf(racc.x, wgt, acc.x);
        acc.y = fmaf(racc.y, wgt, acc.y);
        acc.z = fmaf(racc.z, wgt, acc.z);
        acc.w = fmaf(racc.w, wgt, acc.w);
    }

    acc.x = fmaxf(acc.x, 0.f);
    acc.y = fmaxf(acc.y, 0.f);
    acc.z = fmaxf(acc.z, 0.f);
    acc.w = fmaxf(acc.w, 0.f);

    float s  = acc.x + acc.y + acc.z + acc.w;
    float ss = acc.x * acc.x + acc.y * acc.y + acc.z * acc.z + acc.w * acc.w;
#pragma unroll
    for (int o2 = 32; o2 > 0; o2 >>= 1) {
        s  += __shfl_xor(s, o2, 64);
        ss += __shfl_xor(ss, o2, 64);
    }
    float mean = s * (1.0f / D);
    float var  = ss * (1.0f / D) - mean * mean;
    float inv  = rsqrtf(var + LN_EPS);

    float4 gm = ((const float4*)gamma)[lane];
    float4 bt = ((const float4*)beta)[lane];
    float4 rv;
    rv.x = (acc.x - mean) * inv * gm.x + bt.x;
    rv.y = (acc.y - mean) * inv * gm.y + bt.y;
    rv.z = (acc.z - mean) * inv * gm.z + bt.z;
    rv.w = (acc.w - mean) * inv * gm.w + bt.w;
    ((float4*)out)[(size_t)node * 64 + lane] = rv;
}

// ---------------------------------------------------------------------------
extern "C" void kernel_launch(void* const* d_in, const int* in_sizes, int n_in,
                              void* d_out, int out_size, void* d_ws, size_t ws_size,
                              hipStream_t stream) {
    const float* feat  = (const float*)d_in[0];
    const float* W0    = (const float*)d_in[1];
    const float* W1    = (const float*)d_in[2];
    const float* W2    = (const float*)d_in[3];
    // d_in[4..6] = a0,a1,a2: unused — attention weights are exactly 1/3
    const float* gamma = (const float*)d_in[7];
    const float* beta  = (const float*)d_in[8];
    const int* src0 = (const int*)d_in[9];
    const int* dst0 = (const int*)d_in[10];
    const int* src1 = (const int*)d_in[11];
    const int* dst1 = (const int*)d_in[12];
    const int* src2 = (const int*)d_in[13];
    const int* dst2 = (const int*)d_in[14];
    float* out = (float*)d_out;

    // workspace: h bf16 [12.8M us] | Wt bf16 [64K us] | deg|off|bsum|eidx ints
    unsigned short* h  = (unsigned short*)d_ws;
    unsigned short* Wt = h + (size_t)N_NODES * D;
    int* deg  = (int*)(Wt + D * D);
    int* off  = deg + SCAN_N;
    int* bsum = off + SCAN_N;
    int* eidx = bsum + 256;

    hipMemsetAsync(deg, 0, SCAN_N * sizeof(int), stream);

    k_prep<<<256 + DEG_NB, 256, 0, stream>>>(W0, W1, W2, Wt,
                                             dst0, dst1, dst2, deg);
    k_scan1<<<SCAN_NB, 256, 0, stream>>>(deg, off, bsum);
    k_scan2<<<1, 256, 0, stream>>>(bsum);
    k_fill<<<(3 * E_EDGES + 255) / 256, 256, 0, stream>>>(src0, dst0, src1, dst1,
                                                          src2, dst2, off, bsum, eidx);
    k_gemm<<<(N_NODES + GB_ROWS - 1) / GB_ROWS, 128, 0, stream>>>(feat, Wt, h);
    k_gather<<<(N_NODES + 3) / 4, 256, 0, stream>>>(h, eidx, off, bsum, deg,
                                                    gamma, beta, out);
}

// Round 6
// 356.212 us; speedup vs baseline: 11.9236x; 1.1374x over previous
//
#include <hip/hip_runtime.h>

#define N_NODES 50000
#define D       256
#define E_EDGES 400000
#define LN_EPS  1e-5f

#define SCAN_N  (3 * N_NODES)                       // 150000
#define SCAN_B  1024
#define SCAN_NB ((SCAN_N + SCAN_B - 1) / SCAN_B)    // 147

#define NQ      (3 * E_EDGES / 4)                   // 300000 edge-quads
#define QNB     ((NQ + 255) / 256)                  // 1172
#define E_Q     (E_EDGES / 4)                       // 100000 quads/relation

typedef __attribute__((ext_vector_type(8))) short bf16x8;
typedef __attribute__((ext_vector_type(4))) float f32x4;

__device__ __forceinline__ unsigned short f2bf(float f) {
    unsigned int x = __float_as_uint(f);
    x += 0x7fffu + ((x >> 16) & 1u);     // RNE
    return (unsigned short)(x >> 16);
}

// ---------------------------------------------------------------------------
// Merged prep:
//   blocks [0,256):        Wt[n][k] = bf16((W0+W1+W2)[k][n]/3)  (MFMA B, transposed)
//   blocks [256,256+QNB):  deg count + per-edge rank (atomicAdd return value).
//                          4 edges/thread, int4 loads, 4 independent atomics.
// (softmax of size-1 tensors == 1; softmax([1,1,1]) == exactly 1/3 each)
// ---------------------------------------------------------------------------
__global__ __launch_bounds__(256) void k_prep(const float* __restrict__ W0,
                                              const float* __restrict__ W1,
                                              const float* __restrict__ W2,
                                              unsigned short* __restrict__ Wt,
                                              const int* __restrict__ dst0,
                                              const int* __restrict__ dst1,
                                              const int* __restrict__ dst2,
                                              int* __restrict__ deg,
                                              int* __restrict__ rank) {
    int b = blockIdx.x;
    if (b < 256) {
        int i = b * 256 + threadIdx.x;          // i = n*256 + k
        int n = i >> 8, k = i & 255;
        float v = (W0[k * D + n] + W1[k * D + n] + W2[k * D + n]) * (1.0f / 3.0f);
        Wt[i] = f2bf(v);
    } else {
        int q = (b - 256) * 256 + threadIdx.x;  // quad id
        if (q >= NQ) return;
        int r = q / E_Q;
        int j4 = (q - r * E_Q) * 4;             // edge offset within relation
        const int* dp = (r == 0) ? dst0 : (r == 1) ? dst1 : dst2;
        int4 d4 = *(const int4*)(dp + j4);
        int base = r * N_NODES;
        int4 rk;
        rk.x = atomicAdd(&deg[base + d4.x], 1);
        rk.y = atomicAdd(&deg[base + d4.y], 1);
        rk.z = atomicAdd(&deg[base + d4.z], 1);
        rk.w = atomicAdd(&deg[base + d4.w], 1);
        *(int4*)(rank + q * 4) = rk;
    }
}

// ---------------------------------------------------------------------------
// Prefix sum of deg[SCAN_N]: off = block-LOCAL exclusive scan; bsum = per-
// block sums, turned into exclusive bases by the LAST block to finish
// (device-fence + atomic-flag pattern; one dispatch total).
// Global offset = off[i] + bsum[i>>10].
// ---------------------------------------------------------------------------
__global__ __launch_bounds__(256) void k_scan(const int* __restrict__ deg,
                                              int* __restrict__ off,
                                              int* __restrict__ bsum,
                                              int* __restrict__ flag) {
    __shared__ int wsum[4];
    __shared__ int amLast;
    const int t = threadIdx.x;
    const int base = blockIdx.x * SCAN_B + t * 4;
    int4 v = make_int4(0, 0, 0, 0);
    if (base < SCAN_N) v = *(const int4*)(deg + base);
    const int s1 = v.x + v.y;
    const int s2 = s1 + v.z;
    const int s3 = s2 + v.w;
    const int lane = t & 63;
    int x = s3;
#pragma unroll
    for (int o2 = 1; o2 < 64; o2 <<= 1) {
        int y = __shfl_up(x, o2, 64);
        if (lane >= o2) x += y;
    }
    if (lane == 63) wsum[t >> 6] = x;
    const int texcl = x - s3;
    __syncthreads();
    int wbase = 0;
#pragma unroll
    for (int wi = 0; wi < 4; ++wi)
        if (wi < (t >> 6)) wbase += wsum[wi];
    const int ex = wbase + texcl;
    if (base < SCAN_N) {
        int4 o4;
        o4.x = ex; o4.y = ex + v.x; o4.z = ex + s1; o4.w = ex + s2;
        *(int4*)(off + base) = o4;
    }
    if (t == 0) bsum[blockIdx.x] = wsum[0] + wsum[1] + wsum[2] + wsum[3];

    // ---- last-done block scans the 147 block sums in-place ----
    __threadfence();                               // publish bsum write
    if (t == 0) amLast = (atomicAdd(flag, 1) == (int)gridDim.x - 1);
    __syncthreads();
    if (!amLast) return;
    __threadfence();                               // acquire others' bsum
    int bv = (t < SCAN_NB) ? ((volatile int*)bsum)[t] : 0;
    __syncthreads();                               // wsum reuse hazard
    int y2 = bv;
#pragma unroll
    for (int o2 = 1; o2 < 64; o2 <<= 1) {
        int z = __shfl_up(y2, o2, 64);
        if (lane >= o2) y2 += z;
    }
    if (lane == 63) wsum[t >> 6] = y2;
    __syncthreads();
    int wb2 = 0;
#pragma unroll
    for (int wi = 0; wi < 4; ++wi)
        if (wi < (t >> 6)) wb2 += wsum[wi];
    if (t < SCAN_NB) bsum[t] = wb2 + y2 - bv;      // exclusive base
}

// ---------------------------------------------------------------------------
// Bucket fill, ATOMIC-FREE: pos = off[bucket] + bsum[blk] + rank[edge].
// 4 edges/thread, int4 loads of src/dst/rank.
// ---------------------------------------------------------------------------
__global__ __launch_bounds__(256) void k_fill(const int* __restrict__ src0,
                                              const int* __restrict__ dst0,
                                              const int* __restrict__ src1,
                                              const int* __restrict__ dst1,
                                              const int* __restrict__ src2,
                                              const int* __restrict__ dst2,
                                              const int* __restrict__ off,
                                              const int* __restrict__ bsum,
                                              const int* __restrict__ rank,
                                              int* __restrict__ eidx) {
    int q = blockIdx.x * 256 + threadIdx.x;
    if (q >= NQ) return;
    int r = q / E_Q;
    int j4 = (q - r * E_Q) * 4;
    const int* sp = (r == 0) ? src0 : (r == 1) ? src1 : src2;
    const int* dp = (r == 0) ? dst0 : (r == 1) ? dst1 : dst2;
    int4 s4 = *(const int4*)(sp + j4);
    int4 d4 = *(const int4*)(dp + j4);
    int4 rk = *(const int4*)(rank + q * 4);
    int base = r * N_NODES;
    int i0 = base + d4.x, i1 = base + d4.y, i2 = base + d4.z, i3 = base + d4.w;
    int p0 = off[i0] + bsum[i0 >> 10] + rk.x;
    int p1 = off[i1] + bsum[i1 >> 10] + rk.y;
    int p2 = off[i2] + bsum[i2 >> 10] + rk.z;
    int p3 = off[i3] + bsum[i3 >> 10] + rk.w;
    eidx[p0] = s4.x;
    eidx[p1] = s4.y;
    eidx[p2] = s4.z;
    eidx[p3] = s4.w;
}

// ---------------------------------------------------------------------------
// MFMA GEMM: h_bf16 = bf16(feat) @ Wt^T   (unchanged from R5: 32-row /
// 128-thread blocks, grid 1563, 16-deep batched B-fragment loads)
// ---------------------------------------------------------------------------
#define GB_ROWS 32
__global__ __launch_bounds__(128, 3) void k_gemm(const float* __restrict__ feat,
                                                 const unsigned short* __restrict__ Wt,
                                                 unsigned short* __restrict__ h) {
    __shared__ unsigned short sA[GB_ROWS][D + 8];   // +8 bf16 pad = 16B
    const int t = threadIdx.x;
    const int row0 = blockIdx.x * GB_ROWS;

    const float4* feat4 = (const float4*)feat;
#pragma unroll
    for (int i = 0; i < 16; ++i) {
        int c = i * 128 + t;
        int r = c >> 6, c4 = c & 63;
        float4 v = make_float4(0.f, 0.f, 0.f, 0.f);
        if (row0 + r < N_NODES) v = feat4[(size_t)(row0 + r) * 64 + c4];
        ushort4 p;
        p.x = f2bf(v.x); p.y = f2bf(v.y); p.z = f2bf(v.z); p.w = f2bf(v.w);
        *(ushort4*)&sA[r][c4 * 4] = p;
    }
    __syncthreads();

    const int lane = t & 63;
    const int w    = t >> 6;
    const int lr   = lane & 15;
    const int lq   = lane >> 4;

    f32x4 acc[16];
#pragma unroll
    for (int tt = 0; tt < 16; ++tt) acc[tt] = (f32x4){0.f, 0.f, 0.f, 0.f};

    const bf16x8* WtV = (const bf16x8*)Wt;
#pragma unroll
    for (int ks = 0; ks < 8; ++ks) {
        bf16x8 bfr[16];
#pragma unroll
        for (int tt = 0; tt < 16; ++tt)
            bfr[tt] = WtV[(tt * 16 + lr) * 32 + ks * 4 + lq];
        bf16x8 af = *(const bf16x8*)&sA[w * 16 + lr][ks * 32 + lq * 8];
#pragma unroll
        for (int tt = 0; tt < 16; ++tt)
            acc[tt] = __builtin_amdgcn_mfma_f32_16x16x32_bf16(af, bfr[tt], acc[tt], 0, 0, 0);
    }

#pragma unroll
    for (int tt = 0; tt < 16; ++tt) {
#pragma unroll
        for (int j = 0; j < 4; ++j)
            sA[w * 16 + lq * 4 + j][tt * 16 + lr] = f2bf(acc[tt][j]);
    }
    __syncthreads();

#pragma unroll
    for (int i = 0; i < 8; ++i) {
        int c = i * 128 + t;
        int r = c >> 5, cc = c & 31;
        if (row0 + r < N_NODES) {
            uint4 v = *(const uint4*)&sA[r][cc * 8];
            *(uint4*)(h + (size_t)(row0 + r) * D + cc * 8) = v;
        }
    }
}

// ---------------------------------------------------------------------------
// Fused gather + ReLU + LayerNorm, 8-deep edge unroll.
// off[] is the pristine exclusive start; end = start + deg.
// ---------------------------------------------------------------------------
__device__ __forceinline__ void bf2x4_acc(uint2 u, float4& a) {
    a.x += __uint_as_float(u.x << 16);
    a.y += __uint_as_float(u.x & 0xffff0000u);
    a.z += __uint_as_float(u.y << 16);
    a.w += __uint_as_float(u.y & 0xffff0000u);
}

__global__ __launch_bounds__(256) void k_gather(const unsigned short* __restrict__ h,
                                                const int* __restrict__ eidx,
                                                const int* __restrict__ off,
                                                const int* __restrict__ bsum,
                                                const int* __restrict__ deg,
                                                const float* __restrict__ gamma,
                                                const float* __restrict__ beta,
                                                float* __restrict__ out) {
    int node = blockIdx.x * 4 + (threadIdx.x >> 6);
    if (node >= N_NODES) return;
    int lane = threadIdx.x & 63;
    const uint2* h2 = (const uint2*)h;

    float4 acc = make_float4(0.f, 0.f, 0.f, 0.f);
#pragma unroll
    for (int r = 0; r < 3; ++r) {
        int idx = r * N_NODES + node;
        int dg = deg[idx];
        int start = off[idx] + bsum[idx >> 10];
        int end = start + dg;
        float wgt = 1.0f / (3.0f * (float)(dg > 1 ? dg : 1));
        float4 racc = make_float4(0.f, 0.f, 0.f, 0.f);

        int k = start;
        for (; k + 8 <= end; k += 8) {
            int s[8];
#pragma unroll
            for (int u = 0; u < 8; ++u) s[u] = eidx[k + u];
            uint2 v[8];
#pragma unroll
            for (int u = 0; u < 8; ++u) v[u] = h2[(size_t)s[u] * 64 + lane];
#pragma unroll
            for (int u = 0; u < 8; ++u) bf2x4_acc(v[u], racc);
        }
        if (k + 4 <= end) {
            int s[4];
#pragma unroll
            for (int u = 0; u < 4; ++u) s[u] = eidx[k + u];
            uint2 v[4];
#pragma unroll
            for (int u = 0; u < 4; ++u) v[u] = h2[(size_t)s[u] * 64 + lane];
#pragma unroll
            for (int u = 0; u < 4; ++u) bf2x4_acc(v[u], racc);
            k += 4;
        }
        for (; k < end; ++k) {
            int s = eidx[k];
            uint2 u = h2[(size_t)s * 64 + lane];
            bf2x4_acc(u, racc);
        }
        acc.x = fmaf(racc.x, wgt, acc.x);
        acc.y = fmaf(racc.y, wgt, acc.y);
        acc.z = fmaf(racc.z, wgt, acc.z);
        acc.w = fmaf(racc.w, wgt, acc.w);
    }

    acc.x = fmaxf(acc.x, 0.f);
    acc.y = fmaxf(acc.y, 0.f);
    acc.z = fmaxf(acc.z, 0.f);
    acc.w = fmaxf(acc.w, 0.f);

    float s  = acc.x + acc.y + acc.z + acc.w;
    float ss = acc.x * acc.x + acc.y * acc.y + acc.z * acc.z + acc.w * acc.w;
#pragma unroll
    for (int o2 = 32; o2 > 0; o2 >>= 1) {
        s  += __shfl_xor(s, o2, 64);
        ss += __shfl_xor(ss, o2, 64);
    }
    float mean = s * (1.0f / D);
    float var  = ss * (1.0f / D) - mean * mean;
    float inv  = rsqrtf(var + LN_EPS);

    float4 gm = ((const float4*)gamma)[lane];
    float4 bt = ((const float4*)beta)[lane];
    float4 rv;
    rv.x = (acc.x - mean) * inv * gm.x + bt.x;
    rv.y = (acc.y - mean) * inv * gm.y + bt.y;
    rv.z = (acc.z - mean) * inv * gm.z + bt.z;
    rv.w = (acc.w - mean) * inv * gm.w + bt.w;
    ((float4*)out)[(size_t)node * 64 + lane] = rv;
}

// ---------------------------------------------------------------------------
extern "C" void kernel_launch(void* const* d_in, const int* in_sizes, int n_in,
                              void* d_out, int out_size, void* d_ws, size_t ws_size,
                              hipStream_t stream) {
    const float* feat  = (const float*)d_in[0];
    const float* W0    = (const float*)d_in[1];
    const float* W1    = (const float*)d_in[2];
    const float* W2    = (const float*)d_in[3];
    // d_in[4..6] = a0,a1,a2: unused — attention weights are exactly 1/3
    const float* gamma = (const float*)d_in[7];
    const float* beta  = (const float*)d_in[8];
    const int* src0 = (const int*)d_in[9];
    const int* dst0 = (const int*)d_in[10];
    const int* src1 = (const int*)d_in[11];
    const int* dst1 = (const int*)d_in[12];
    const int* src2 = (const int*)d_in[13];
    const int* dst2 = (const int*)d_in[14];
    float* out = (float*)d_out;

    // workspace layout (16B-aligned segments):
    // h bf16 [N*D] | Wt bf16 [D*D] | deg[150000] | flag+pad[4] | off[150000]
    // | bsum[256] | rank[1.2M] | eidx[1.2M]
    unsigned short* h  = (unsigned short*)d_ws;
    unsigned short* Wt = h + (size_t)N_NODES * D;
    int* deg  = (int*)(Wt + D * D);
    int* flag = deg + SCAN_N;          // 4-int slot (flag + pad)
    int* off  = flag + 4;
    int* bsum = off + SCAN_N;
    int* eidx = bsum + 256;
    int* rank = eidx + 3 * E_EDGES;

    // zero deg + flag in one memset
    hipMemsetAsync(deg, 0, (SCAN_N + 4) * sizeof(int), stream);

    k_prep<<<256 + QNB, 256, 0, stream>>>(W0, W1, W2, Wt,
                                          dst0, dst1, dst2, deg, rank);
    k_scan<<<SCAN_NB, 256, 0, stream>>>(deg, off, bsum, flag);
    k_fill<<<QNB, 256, 0, stream>>>(src0, dst0, src1, dst1, src2, dst2,
                                    off, bsum, rank, eidx);
    k_gemm<<<(N_NODES + GB_ROWS - 1) / GB_ROWS, 128, 0, stream>>>(feat, Wt, h);
    k_gather<<<(N_NODES + 3) / 4, 256, 0, stream>>>(h, eidx, off, bsum, deg,
                                                    gamma, beta, out);
}

// Round 9
// 355.173 us; speedup vs baseline: 11.9585x; 1.0029x over previous
//
#include <hip/hip_runtime.h>

#define N_NODES 50000
#define D       256
#define E_EDGES 400000
#define LN_EPS  1e-5f

#define SCAN_N  (3 * N_NODES)                       // 150000
#define SCAN_B  1024
#define SCAN_NB ((SCAN_N + SCAN_B - 1) / SCAN_B)    // 147

#define NQ      (3 * E_EDGES / 4)                   // 300000 edge-quads
#define QNB     ((NQ + 255) / 256)                  // 1172
#define E_Q     (E_EDGES / 4)                       // 100000 quads/relation

#define NE8     (3 * E_EDGES / 8)                   // 150000 edge-octets
#define E_8     (E_EDGES / 8)                       // 50000 octets/relation
#define DEG_NB8 ((NE8 + 255) / 256)                 // 586

typedef __attribute__((ext_vector_type(8))) short bf16x8;
typedef __attribute__((ext_vector_type(4))) float f32x4;

__device__ __forceinline__ unsigned short f2bf(float f) {
    unsigned int x = __float_as_uint(f);
    x += 0x7fffu + ((x >> 16) & 1u);     // RNE
    return (unsigned short)(x >> 16);
}
__device__ __forceinline__ unsigned int pack2(float lo, float hi) {
    return (unsigned int)f2bf(lo) | ((unsigned int)f2bf(hi) << 16);
}

// ---------------------------------------------------------------------------
// Merged prep (R6 structure, deg segment widened to 8 edges/thread):
//   blocks [0, DEG_NB8):  deg count + per-edge rank (atomic return value),
//                         8 edges/thread: 2x int4 dst loads, 8 independent
//                         atomics in flight, 2x int4 rank stores.
//   blocks [DEG_NB8, +256): Wt[n][k] = bf16((W0+W1+W2)[k][n]/3) (MFMA B^T)
// (softmax of size-1 tensors == 1; softmax([1,1,1]) == exactly 1/3 each)
// ---------------------------------------------------------------------------
__global__ __launch_bounds__(256) void k_prep(const float* __restrict__ W0,
                                              const float* __restrict__ W1,
                                              const float* __restrict__ W2,
                                              unsigned short* __restrict__ Wt,
                                              const int* __restrict__ dst0,
                                              const int* __restrict__ dst1,
                                              const int* __restrict__ dst2,
                                              int* __restrict__ deg,
                                              int* __restrict__ rank) {
    int b = blockIdx.x;
    if (b < DEG_NB8) {
        int q8 = b * 256 + threadIdx.x;         // octet id
        if (q8 >= NE8) return;
        int r = q8 / E_8;
        int o = q8 - r * E_8;                   // octet within relation
        int j8 = o * 8;
        const int* dp = (r == 0) ? dst0 : (r == 1) ? dst1 : dst2;
        int4 dA = *(const int4*)(dp + j8);
        int4 dB = *(const int4*)(dp + j8 + 4);
        int base = r * N_NODES;
        int4 ra, rb;
        ra.x = atomicAdd(&deg[base + dA.x], 1);
        ra.y = atomicAdd(&deg[base + dA.y], 1);
        ra.z = atomicAdd(&deg[base + dA.z], 1);
        ra.w = atomicAdd(&deg[base + dA.w], 1);
        rb.x = atomicAdd(&deg[base + dB.x], 1);
        rb.y = atomicAdd(&deg[base + dB.y], 1);
        rb.z = atomicAdd(&deg[base + dB.z], 1);
        rb.w = atomicAdd(&deg[base + dB.w], 1);
        int q = r * E_Q + o * 2;                // global quad id of first int4
        *(int4*)(rank + q * 4)     = ra;
        *(int4*)(rank + q * 4 + 4) = rb;
    } else {
        int i = (b - DEG_NB8) * 256 + threadIdx.x;   // i = n*256 + k
        int n = i >> 8, k = i & 255;
        float v = (W0[k * D + n] + W1[k * D + n] + W2[k * D + n]) * (1.0f / 3.0f);
        Wt[i] = f2bf(v);
    }
}

// ---------------------------------------------------------------------------
// Prefix sum of deg[SCAN_N]: off = block-LOCAL exclusive scan; bsum turned
// into exclusive bases by the last-finished block (fence + atomic flag).
// Global offset = off[i] + bsum[i>>10].   (R6-proven verbatim)
// ---------------------------------------------------------------------------
__global__ __launch_bounds__(256) void k_scan(const int* __restrict__ deg,
                                              int* __restrict__ off,
                                              int* __restrict__ bsum,
                                              int* __restrict__ flag) {
    __shared__ int wsum[4];
    __shared__ int amLast;
    const int t = threadIdx.x;
    const int base = blockIdx.x * SCAN_B + t * 4;
    int4 v = make_int4(0, 0, 0, 0);
    if (base < SCAN_N) v = *(const int4*)(deg + base);
    const int s1 = v.x + v.y;
    const int s2 = s1 + v.z;
    const int s3 = s2 + v.w;
    const int lane = t & 63;
    int x = s3;
#pragma unroll
    for (int o2 = 1; o2 < 64; o2 <<= 1) {
        int y = __shfl_up(x, o2, 64);
        if (lane >= o2) x += y;
    }
    if (lane == 63) wsum[t >> 6] = x;
    const int texcl = x - s3;
    __syncthreads();
    int wbase = 0;
#pragma unroll
    for (int wi = 0; wi < 4; ++wi)
        if (wi < (t >> 6)) wbase += wsum[wi];
    const int ex = wbase + texcl;
    if (base < SCAN_N) {
        int4 o4;
        o4.x = ex; o4.y = ex + v.x; o4.z = ex + s1; o4.w = ex + s2;
        *(int4*)(off + base) = o4;
    }
    if (t == 0) bsum[blockIdx.x] = wsum[0] + wsum[1] + wsum[2] + wsum[3];

    __threadfence();
    if (t == 0) amLast = (atomicAdd(flag, 1) == (int)gridDim.x - 1);
    __syncthreads();
    if (!amLast) return;
    __threadfence();
    int bv = (t < SCAN_NB) ? ((volatile int*)bsum)[t] : 0;
    __syncthreads();
    int y2 = bv;
#pragma unroll
    for (int o2 = 1; o2 < 64; o2 <<= 1) {
        int z = __shfl_up(y2, o2, 64);
        if (lane >= o2) y2 += z;
    }
    if (lane == 63) wsum[t >> 6] = y2;
    __syncthreads();
    int wb2 = 0;
#pragma unroll
    for (int wi = 0; wi < 4; ++wi)
        if (wi < (t >> 6)) wb2 += wsum[wi];
    if (t < SCAN_NB) bsum[t] = wb2 + y2 - bv;
}

// ---------------------------------------------------------------------------
// Bucket fill, atomic-free: pos = off[bucket] + bsum[blk] + rank[edge].
// (R6-proven verbatim)
// ---------------------------------------------------------------------------
__global__ __launch_bounds__(256) void k_fill(const int* __restrict__ src0,
                                              const int* __restrict__ dst0,
                                              const int* __restrict__ src1,
                                              const int* __restrict__ dst1,
                                              const int* __restrict__ src2,
                                              const int* __restrict__ dst2,
                                              const int* __restrict__ off,
                                              const int* __restrict__ bsum,
                                              const int* __restrict__ rank,
                                              int* __restrict__ eidx) {
    int q = blockIdx.x * 256 + threadIdx.x;
    if (q >= NQ) return;
    int r = q / E_Q;
    int j4 = (q - r * E_Q) * 4;
    const int* sp = (r == 0) ? src0 : (r == 1) ? src1 : src2;
    const int* dp = (r == 0) ? dst0 : (r == 1) ? dst1 : dst2;
    int4 s4 = *(const int4*)(sp + j4);
    int4 d4 = *(const int4*)(dp + j4);
    int4 rk = *(const int4*)(rank + q * 4);
    int base = r * N_NODES;
    int i0 = base + d4.x, i1 = base + d4.y, i2 = base + d4.z, i3 = base + d4.w;
    int p0 = off[i0] + bsum[i0 >> 10] + rk.x;
    int p1 = off[i1] + bsum[i1 >> 10] + rk.y;
    int p2 = off[i2] + bsum[i2 >> 10] + rk.z;
    int p3 = off[i3] + bsum[i3 >> 10] + rk.w;
    eidx[p0] = s4.x;
    eidx[p1] = s4.y;
    eidx[p2] = s4.z;
    eidx[p3] = s4.w;
}

// ---------------------------------------------------------------------------
// MFMA GEMM: h_bf16 = bf16(feat) @ Wt^T   (R6-proven verbatim: 32-row /
// 128-thread blocks, grid 1563, 16-deep batched B-fragment loads)
// ---------------------------------------------------------------------------
#define GB_ROWS 32
__global__ __launch_bounds__(128, 3) void k_gemm(const float* __restrict__ feat,
                                                 const unsigned short* __restrict__ Wt,
                                                 unsigned short* __restrict__ h) {
    __shared__ unsigned short sA[GB_ROWS][D + 8];   // +8 bf16 pad = 16B
    const int t = threadIdx.x;
    const int row0 = blockIdx.x * GB_ROWS;

    const float4* feat4 = (const float4*)feat;
#pragma unroll
    for (int i = 0; i < 16; ++i) {
        int c = i * 128 + t;
        int r = c >> 6, c4 = c & 63;
        float4 v = make_float4(0.f, 0.f, 0.f, 0.f);
        if (row0 + r < N_NODES) v = feat4[(size_t)(row0 + r) * 64 + c4];
        ushort4 p;
        p.x = f2bf(v.x); p.y = f2bf(v.y); p.z = f2bf(v.z); p.w = f2bf(v.w);
        *(ushort4*)&sA[r][c4 * 4] = p;
    }
    __syncthreads();

    const int lane = t & 63;
    const int w    = t >> 6;
    const int lr   = lane & 15;
    const int lq   = lane >> 4;

    f32x4 acc[16];
#pragma unroll
    for (int tt = 0; tt < 16; ++tt) acc[tt] = (f32x4){0.f, 0.f, 0.f, 0.f};

    const bf16x8* WtV = (const bf16x8*)Wt;
#pragma unroll
    for (int ks = 0; ks < 8; ++ks) {
        bf16x8 bfr[16];
#pragma unroll
        for (int tt = 0; tt < 16; ++tt)
            bfr[tt] = WtV[(tt * 16 + lr) * 32 + ks * 4 + lq];
        bf16x8 af = *(const bf16x8*)&sA[w * 16 + lr][ks * 32 + lq * 8];
#pragma unroll
        for (int tt = 0; tt < 16; ++tt)
            acc[tt] = __builtin_amdgcn_mfma_f32_16x16x32_bf16(af, bfr[tt], acc[tt], 0, 0, 0);
    }

#pragma unroll
    for (int tt = 0; tt < 16; ++tt) {
#pragma unroll
        for (int j = 0; j < 4; ++j)
            sA[w * 16 + lq * 4 + j][tt * 16 + lr] = f2bf(acc[tt][j]);
    }
    __syncthreads();

#pragma unroll
    for (int i = 0; i < 8; ++i) {
        int c = i * 128 + t;
        int r = c >> 5, cc = c & 31;
        if (row0 + r < N_NODES) {
            uint4 v = *(const uint4*)&sA[r][cc * 8];
            *(uint4*)(h + (size_t)(row0 + r) * D + cc * 8) = v;
        }
    }
}

// ---------------------------------------------------------------------------
// Fused gather + ReLU + LayerNorm, 8/4/1 edge unroll.  (R6-proven verbatim)
// ---------------------------------------------------------------------------
__device__ __forceinline__ void bf2x4_acc(uint2 u, float4& a) {
    a.x += __uint_as_float(u.x << 16);
    a.y += __uint_as_float(u.x & 0xffff0000u);
    a.z += __uint_as_float(u.y << 16);
    a.w += __uint_as_float(u.y & 0xffff0000u);
}

__global__ __launch_bounds__(256) void k_gather(const unsigned short* __restrict__ h,
                                                const int* __restrict__ eidx,
                                                const int* __restrict__ off,
                                                const int* __restrict__ bsum,
                                                const int* __restrict__ deg,
                                                const float* __restrict__ gamma,
                                                const float* __restrict__ beta,
                                                float* __restrict__ out) {
    int node = blockIdx.x * 4 + (threadIdx.x >> 6);
    if (node >= N_NODES) return;
    int lane = threadIdx.x & 63;
    const uint2* h2 = (const uint2*)h;

    float4 acc = make_float4(0.f, 0.f, 0.f, 0.f);
#pragma unroll
    for (int r = 0; r < 3; ++r) {
        int idx = r * N_NODES + node;
        int dg = deg[idx];
        int start = off[idx] + bsum[idx >> 10];
        int end = start + dg;
        float wgt = 1.0f / (3.0f * (float)(dg > 1 ? dg : 1));
        float4 racc = make_float4(0.f, 0.f, 0.f, 0.f);

        int k = start;
        for (; k + 8 <= end; k += 8) {
            int s[8];
#pragma unroll
            for (int u = 0; u < 8; ++u) s[u] = eidx[k + u];
            uint2 v[8];
#pragma unroll
            for (int u = 0; u < 8; ++u) v[u] = h2[(size_t)s[u] * 64 + lane];
#pragma unroll
            for (int u = 0; u < 8; ++u) bf2x4_acc(v[u], racc);
        }
        if (k + 4 <= end) {
            int s[4];
#pragma unroll
            for (int u = 0; u < 4; ++u) s[u] = eidx[k + u];
            uint2 v[4];
#pragma unroll
            for (int u = 0; u < 4; ++u) v[u] = h2[(size_t)s[u] * 64 + lane];
#pragma unroll
            for (int u = 0; u < 4; ++u) bf2x4_acc(v[u], racc);
            k += 4;
        }
        for (; k < end; ++k) {
            int s = eidx[k];
            uint2 u = h2[(size_t)s * 64 + lane];
            bf2x4_acc(u, racc);
        }
        acc.x = fmaf(racc.x, wgt, acc.x);
        acc.y = fmaf(racc.y, wgt, acc.y);
        acc.z = fmaf(racc.z, wgt, acc.z);
        acc.w = fmaf(racc.w, wgt, acc.w);
    }

    acc.x = fmaxf(acc.x, 0.f);
    acc.y = fmaxf(acc.y, 0.f);
    acc.z = fmaxf(acc.z, 0.f);
    acc.w = fmaxf(acc.w, 0.f);

    float s  = acc.x + acc.y + acc.z + acc.w;
    float ss = acc.x * acc.x + acc.y * acc.y + acc.z * acc.z + acc.w * acc.w;
#pragma unroll
    for (int o2 = 32; o2 > 0; o2 >>= 1) {
        s  += __shfl_xor(s, o2, 64);
        ss += __shfl_xor(ss, o2, 64);
    }
    float mean = s * (1.0f / D);
    float var  = ss * (1.0f / D) - mean * mean;
    float inv  = rsqrtf(var + LN_EPS);

    float4 gm = ((const float4*)gamma)[lane];
    float4 bt = ((const float4*)beta)[lane];
    float4 rv;
    rv.x = (acc.x - mean) * inv * gm.x + bt.x;
    rv.y = (acc.y - mean) * inv * gm.y + bt.y;
    rv.z = (acc.z - mean) * inv * gm.z + bt.z;
    rv.w = (acc.w - mean) * inv * gm.w + bt.w;
    ((float4*)out)[(size_t)node * 64 + lane] = rv;
}

// ---------------------------------------------------------------------------
extern "C" void kernel_launch(void* const* d_in, const int* in_sizes, int n_in,
                              void* d_out, int out_size, void* d_ws, size_t ws_size,
                              hipStream_t stream) {
    const float* feat  = (const float*)d_in[0];
    const float* W0    = (const float*)d_in[1];
    const float* W1    = (const float*)d_in[2];
    const float* W2    = (const float*)d_in[3];
    // d_in[4..6] = a0,a1,a2: unused — attention weights are exactly 1/3
    const float* gamma = (const float*)d_in[7];
    const float* beta  = (const float*)d_in[8];
    const int* src0 = (const int*)d_in[9];
    const int* dst0 = (const int*)d_in[10];
    const int* src1 = (const int*)d_in[11];
    const int* dst1 = (const int*)d_in[12];
    const int* src2 = (const int*)d_in[13];
    const int* dst2 = (const int*)d_in[14];
    float* out = (float*)d_out;

    // workspace (R6 layout): h bf16 [N*D] | Wt bf16 [D*D] | deg[150000] |
    // flag[4] | off[150000] | bsum[256] | eidx[1.2M] | rank[1.2M]  (~36.5 MB)
    unsigned short* h  = (unsigned short*)d_ws;
    unsigned short* Wt = h + (size_t)N_NODES * D;
    int* deg  = (int*)(Wt + D * D);
    int* flag = deg + SCAN_N;
    int* off  = flag + 4;
    int* bsum = off + SCAN_N;
    int* eidx = bsum + 256;
    int* rank = eidx + 3 * E_EDGES;

    hipMemsetAsync(deg, 0, (SCAN_N + 4) * sizeof(int), stream);

    k_prep<<<DEG_NB8 + 256, 256, 0, stream>>>(W0, W1, W2, Wt,
                                              dst0, dst1, dst2, deg, rank);
    k_scan<<<SCAN_NB, 256, 0, stream>>>(deg, off, bsum, flag);
    k_fill<<<QNB, 256, 0, stream>>>(src0, dst0, src1, dst1, src2, dst2,
                                    off, bsum, rank, eidx);
    k_gemm<<<(N_NODES + GB_ROWS - 1) / GB_ROWS, 128, 0, stream>>>(feat, Wt, h);
    k_gather<<<(N_NODES + 3) / 4, 256, 0, stream>>>(h, eidx, off, bsum, deg,
                                                    gamma, beta, out);
}